// Round 11
// baseline (965.238 us; speedup 1.0000x reference)
//
#include <hip/hip_runtime.h>

#define N_NODES 100000
#define N_EDGES 1600000
#define N_GRAPHS 512
#define F_IN 64
#define HD 256
#define EXTRA 16
#define SCAN_BLOCK 512

typedef float f32x4 __attribute__((ext_vector_type(4)));
typedef _Float16 f16x4 __attribute__((ext_vector_type(4)));
typedef _Float16 f16x8 __attribute__((ext_vector_type(8)));

__device__ __forceinline__ float selu_f(float x) {
    const float a = 1.6732632423543772f, sc = 1.0507009873554805f;
    return x > 0.f ? sc * x : sc * a * (__expf(x) - 1.f);
}

// ---------------- CSR build ----------------
__global__ __launch_bounds__(256) void hist_k(const int* __restrict__ dst, int* __restrict__ hist) {
    int j = blockIdx.x * 256 + threadIdx.x;
    if (j < N_EDGES) atomicAdd(&hist[dst[j]], 1);
}

__global__ __launch_bounds__(SCAN_BLOCK) void scan1_k(const int* __restrict__ hist,
                                                      int* __restrict__ row_ptr,
                                                      int* __restrict__ bsums) {
    __shared__ int sm[SCAN_BLOCK];
    int t = threadIdx.x;
    int i = blockIdx.x * SCAN_BLOCK + t;
    int v = (i < N_NODES) ? hist[i] : 0;
    sm[t] = v;
    __syncthreads();
    for (int off = 1; off < SCAN_BLOCK; off <<= 1) {
        int add = (t >= off) ? sm[t - off] : 0;
        __syncthreads();
        sm[t] += add;
        __syncthreads();
    }
    if (i < N_NODES) row_ptr[i] = sm[t] - v;
    if (t == SCAN_BLOCK - 1) bsums[blockIdx.x] = sm[t];
}

__global__ __launch_bounds__(256) void scan2_k(int* __restrict__ bsums, int nb) {
    __shared__ int sm[256];
    int t = threadIdx.x;
    int v = (t < nb) ? bsums[t] : 0;
    sm[t] = v;
    __syncthreads();
    for (int off = 1; off < 256; off <<= 1) {
        int add = (t >= off) ? sm[t - off] : 0;
        __syncthreads();
        sm[t] += add;
        __syncthreads();
    }
    if (t < nb) bsums[t] = sm[t] - v;
}

__global__ __launch_bounds__(256) void scan3_k(int* __restrict__ row_ptr, const int* __restrict__ bsums,
                                               int* __restrict__ cursor) {
    int i = blockIdx.x * 256 + threadIdx.x;
    if (i < N_NODES) {
        int r = row_ptr[i] + bsums[i / SCAN_BLOCK];
        row_ptr[i] = r;
        cursor[i] = r;
    }
    if (i == 0) row_ptr[N_NODES] = N_EDGES;
}

__global__ __launch_bounds__(256) void scatter_k(const int* __restrict__ src,
                                                 const int* __restrict__ dst,
                                                 int* __restrict__ cursor,
                                                 int* __restrict__ csr_src) {
    int j = blockIdx.x * 256 + threadIdx.x;
    if (j < N_EDGES) {
        int r = atomicAdd(&cursor[dst[j]], 1);
        csr_src[r] = src[j];
    }
}

__global__ __launch_bounds__(256) void gbound_k(const int* __restrict__ node_graph, int* __restrict__ gstart) {
    int g = blockIdx.x * 256 + threadIdx.x;
    if (g > N_GRAPHS) return;
    int lo = 0, hi = N_NODES;
    while (lo < hi) {
        int mid = (lo + hi) >> 1;
        if (node_graph[mid] < g) lo = mid + 1; else hi = mid;
    }
    gstart[g] = lo;
}

// ---------------- splits/casts ----------------
__global__ __launch_bounds__(256) void tcast_split_k(const float* __restrict__ W,
                                                     _Float16* __restrict__ Wt_hi,
                                                     _Float16* __restrict__ Wt_lo, int K) {
    int idx = blockIdx.x * 256 + threadIdx.x;
    if (idx >= K * HD) return;
    int n = idx / K, k = idx - n * K;
    float w = W[(size_t)k * HD + n];
    _Float16 hi = (_Float16)w;
    _Float16 lo = (_Float16)(w - (float)hi);
    Wt_hi[idx] = hi;
    Wt_lo[idx] = lo;
}

__global__ __launch_bounds__(256) void split_cast_k(const float* __restrict__ in,
                                                    _Float16* __restrict__ hi,
                                                    _Float16* __restrict__ lo, int n4) {
    int i = blockIdx.x * 256 + threadIdx.x;
    if (i >= n4) return;
    float4 v = *(const float4*)(in + (size_t)i * 4);
    f16x4 h, l;
    h.x = (_Float16)v.x; l.x = (_Float16)(v.x - (float)h.x);
    h.y = (_Float16)v.y; l.y = (_Float16)(v.y - (float)h.y);
    h.z = (_Float16)v.z; l.z = (_Float16)(v.z - (float)h.z);
    h.w = (_Float16)v.w; l.w = (_Float16)(v.w - (float)h.w);
    *(f16x4*)(hi + (size_t)i * 4) = h;
    *(f16x4*)(lo + (size_t)i * 4) = l;
}

// ---------------- split-f16 MFMA GEMM: 2x2 wave tiling, pipelined staging ----------------
// Each wave owns a 64x64 output sub-tile (4 m-frags x 4 n-frags): 16 ds_read_b128 vs 48 MFMA/iter.
template <int K>
__global__ __launch_bounds__(256) void gemm_split_k(const _Float16* __restrict__ Ahi,
                                                    const _Float16* __restrict__ Alo,
                                                    const _Float16* __restrict__ Bt_hi,
                                                    const _Float16* __restrict__ Bt_lo,
                                                    const float* __restrict__ al,
                                                    const float* __restrict__ ar,
                                                    _Float16* __restrict__ Chi,
                                                    float* __restrict__ el,
                                                    float* __restrict__ er, int M) {
    const int BM = 128, BN = 128, LDP = 40;
    __shared__ _Float16 As_hi[BM][LDP];
    __shared__ _Float16 As_lo[BM][LDP];
    __shared__ _Float16 Bs_hi[BN][LDP];
    __shared__ _Float16 Bs_lo[BN][LDP];
    int tid = threadIdx.x;
    int wave = tid >> 6, lane = tid & 63;
    int wr = wave >> 1, wc = wave & 1;   // 2x2 wave grid
    int q = lane >> 4, l16 = lane & 15;
    int row0 = blockIdx.y * BM, col0 = blockIdx.x * BN;
    f32x4 acc[4][4] = {};

    // staging: thread covers rows sr and sr+64 (8 f16 = 16 B chunks)
    int sr = tid >> 2, so = (tid & 3) * 8;
    f16x8 rAh[2], rAl[2], rBh[2], rBl[2];

    auto load_tile = [&](int k0) {
#pragma unroll
        for (int c = 0; c < 2; c++) {
            int r = sr + 64 * c;
            int gr = row0 + r;
            f16x8 vh = {}, vl = {};
            if (gr < M) {
                vh = *(const f16x8*)(Ahi + (size_t)gr * K + k0 + so);
                vl = *(const f16x8*)(Alo + (size_t)gr * K + k0 + so);
            }
            rAh[c] = vh; rAl[c] = vl;
            int gb = col0 + r;
            rBh[c] = *(const f16x8*)(Bt_hi + (size_t)gb * K + k0 + so);
            rBl[c] = *(const f16x8*)(Bt_lo + (size_t)gb * K + k0 + so);
        }
    };
    auto store_tile = [&]() {
#pragma unroll
        for (int c = 0; c < 2; c++) {
            int r = sr + 64 * c;
            *(f16x8*)&As_hi[r][so] = rAh[c];
            *(f16x8*)&As_lo[r][so] = rAl[c];
            *(f16x8*)&Bs_hi[r][so] = rBh[c];
            *(f16x8*)&Bs_lo[r][so] = rBl[c];
        }
    };

    load_tile(0);
    store_tile();
    __syncthreads();

    for (int k0 = 0; k0 < K; k0 += 32) {
        bool more = (k0 + 32) < K;
        if (more) load_tile(k0 + 32);  // in flight during MFMA below

        f16x8 ah[4], alo2[4], bh[4], bl[4];
#pragma unroll
        for (int mf = 0; mf < 4; mf++) {
            int m = wr * 64 + mf * 16 + l16;
            ah[mf] = *(const f16x8*)&As_hi[m][q * 8];
            alo2[mf] = *(const f16x8*)&As_lo[m][q * 8];
        }
#pragma unroll
        for (int nf = 0; nf < 4; nf++) {
            int n = wc * 64 + nf * 16 + l16;
            bh[nf] = *(const f16x8*)&Bs_hi[n][q * 8];
            bl[nf] = *(const f16x8*)&Bs_lo[n][q * 8];
        }
#pragma unroll
        for (int mf = 0; mf < 4; mf++)
#pragma unroll
            for (int nf = 0; nf < 4; nf++) {
                acc[mf][nf] = __builtin_amdgcn_mfma_f32_16x16x32_f16(ah[mf], bh[nf], acc[mf][nf], 0, 0, 0);
                acc[mf][nf] = __builtin_amdgcn_mfma_f32_16x16x32_f16(ah[mf], bl[nf], acc[mf][nf], 0, 0, 0);
                acc[mf][nf] = __builtin_amdgcn_mfma_f32_16x16x32_f16(alo2[mf], bh[nf], acc[mf][nf], 0, 0, 0);
            }
        if (more) {
            __syncthreads();
            store_tile();
            __syncthreads();
        }
    }

    // epilogue: wave (wr,wc) covers rows wr*64.., cols wc*64.. = exactly head h0+wc
    const int hh = (col0 >> 6) + wc;
    float alv[4], arv[4];
#pragma unroll
    for (int nf = 0; nf < 4; nf++) {
        int d = nf * 16 + l16;
        alv[nf] = al[hh * 64 + d];
        arv[nf] = ar[hh * 64 + d];
    }
#pragma unroll
    for (int mf = 0; mf < 4; mf++) {
#pragma unroll
        for (int i = 0; i < 4; i++) {
            int r = row0 + wr * 64 + mf * 16 + q * 4 + i;
            bool ok = r < M;
            float e_l = 0.f, e_r = 0.f;
#pragma unroll
            for (int nf = 0; nf < 4; nf++) {
                float v = acc[mf][nf][i];
                if (ok) Chi[(size_t)r * HD + col0 + wc * 64 + nf * 16 + l16] = (_Float16)v;
                e_l = fmaf(v, alv[nf], e_l);
                e_r = fmaf(v, arv[nf], e_r);
            }
#pragma unroll
            for (int off = 1; off < 16; off <<= 1) {
                e_l += __shfl_xor(e_l, off, 64);
                e_r += __shfl_xor(e_r, off, 64);
            }
            if (l16 == 0 && ok) {
                el[(size_t)r * 4 + hh] = e_l;
                er[(size_t)r * 4 + hh] = e_r;
            }
        }
    }
}

// ---------------- GAT aggregation (R9: barrier-free, 8-deep prefetch) ----------------
// OUT=0: write x as hi/lo f16 split. OUT=1: write fp32 x + fused sigmoid score.
template <int OUT>
__global__ __launch_bounds__(256) void gat_aggregate_k(const _Float16* __restrict__ hb,
                                                       const float* __restrict__ el,
                                                       const float* __restrict__ er,
                                                       const int* __restrict__ csr_src,
                                                       const int* __restrict__ row_ptr,
                                                       const float* __restrict__ bias,
                                                       _Float16* __restrict__ xhi,
                                                       _Float16* __restrict__ xlo,
                                                       float* __restrict__ xf32,
                                                       const float* __restrict__ sw,
                                                       const float* __restrict__ sb,
                                                       float* __restrict__ wsc) {
    __shared__ float wlds[4][64][4];
    __shared__ int snlds[4][64];
    int wv = threadIdx.x >> 6;
    int lane = threadIdx.x & 63;
    int v = blockIdx.x * 4 + wv;
    bool valid = v < N_NODES;
    int vc = valid ? v : 0;
    int rs = row_ptr[vc];
    int deg = valid ? row_ptr[vc + 1] - rs : 0;
    float4 erv = make_float4(0.f, 0.f, 0.f, 0.f);
    if (valid) erv = *(const float4*)(er + (size_t)vc * 4);

    int head = lane >> 4;
    float inv_den = 1.f;
    float m_h = 0.f, er_h = 0.f;
    f16x4 hv_pre[8];
    int nb0 = 0;

    if (deg <= 64) {
        float e0 = -1e30f, e1 = -1e30f, e2 = -1e30f, e3 = -1e30f;
        int my_sn = 0;
        if (lane < deg) {
            my_sn = csr_src[rs + lane];
            float4 elv = *(const float4*)(el + (size_t)my_sn * 4);
            float t0 = elv.x + erv.x, t1 = elv.y + erv.y, t2 = elv.z + erv.z, t3 = elv.w + erv.w;
            e0 = t0 > 0.f ? t0 : 0.2f * t0;
            e1 = t1 > 0.f ? t1 : 0.2f * t1;
            e2 = t2 > 0.f ? t2 : 0.2f * t2;
            e3 = t3 > 0.f ? t3 : 0.2f * t3;
        }
        nb0 = deg < 8 ? deg : 8;
#pragma unroll
        for (int u = 0; u < 8; u++) {
            int snb = __shfl(my_sn, u, 64);
            if (u < nb0) hv_pre[u] = *(const f16x4*)(hb + (size_t)snb * HD + lane * 4);
        }
        float m0 = e0, m1 = e1, m2 = e2, m3 = e3;
        for (int off = 1; off < deg; off <<= 1) {
            m0 = fmaxf(m0, __shfl_xor(m0, off, 64));
            m1 = fmaxf(m1, __shfl_xor(m1, off, 64));
            m2 = fmaxf(m2, __shfl_xor(m2, off, 64));
            m3 = fmaxf(m3, __shfl_xor(m3, off, 64));
        }
        float p0 = 0.f, p1 = 0.f, p2 = 0.f, p3 = 0.f;
        if (lane < deg) {
            p0 = __expf(e0 - m0); p1 = __expf(e1 - m1);
            p2 = __expf(e2 - m2); p3 = __expf(e3 - m3);
        }
        float s0 = p0, s1 = p1, s2 = p2, s3 = p3;
        for (int off = 1; off < deg; off <<= 1) {
            s0 += __shfl_xor(s0, off, 64);
            s1 += __shfl_xor(s1, off, 64);
            s2 += __shfl_xor(s2, off, 64);
            s3 += __shfl_xor(s3, off, 64);
        }
        float d0 = __shfl(s0, 0, 64), d1 = __shfl(s1, 0, 64);
        float d2 = __shfl(s2, 0, 64), d3 = __shfl(s3, 0, 64);
        float dh = head == 0 ? d0 : head == 1 ? d1 : head == 2 ? d2 : d3;
        inv_den = 1.f / fmaxf(dh, 1e-9f);
        if (lane < deg) {
            wlds[wv][lane][0] = p0;
            wlds[wv][lane][1] = p1;
            wlds[wv][lane][2] = p2;
            wlds[wv][lane][3] = p3;
            snlds[wv][lane] = my_sn;
        }
        // no barrier: wave-private LDS slice
    } else {
        float m[4] = {-1e30f, -1e30f, -1e30f, -1e30f};
        float s[4] = {0.f, 0.f, 0.f, 0.f};
        for (int t = lane; t < deg; t += 64) {
            int sn = csr_src[rs + t];
            float4 elv = *(const float4*)(el + (size_t)sn * 4);
            float e[4];
            e[0] = elv.x + erv.x; e[1] = elv.y + erv.y; e[2] = elv.z + erv.z; e[3] = elv.w + erv.w;
#pragma unroll
            for (int hh = 0; hh < 4; hh++) {
                float ev = e[hh] > 0.f ? e[hh] : 0.2f * e[hh];
                float mn = fmaxf(m[hh], ev);
                s[hh] = s[hh] * __expf(m[hh] - mn) + __expf(ev - mn);
                m[hh] = mn;
            }
        }
#pragma unroll
        for (int off = 32; off >= 1; off >>= 1) {
#pragma unroll
            for (int hh = 0; hh < 4; hh++) {
                float mo = __shfl_xor(m[hh], off, 64);
                float so = __shfl_xor(s[hh], off, 64);
                float mn = fmaxf(m[hh], mo);
                s[hh] = s[hh] * __expf(m[hh] - mn) + so * __expf(mo - mn);
                m[hh] = mn;
            }
        }
        m_h = head == 0 ? m[0] : head == 1 ? m[1] : head == 2 ? m[2] : m[3];
        float dh = head == 0 ? s[0] : head == 1 ? s[1] : head == 2 ? s[2] : s[3];
        er_h = head == 0 ? erv.x : head == 1 ? erv.y : head == 2 ? erv.z : erv.w;
        inv_den = 1.f / fmaxf(dh, 1e-9f);
    }

    float a0 = 0.f, a1 = 0.f, a2 = 0.f, a3 = 0.f;
    if (deg <= 64) {
#pragma unroll
        for (int u = 0; u < 8; u++) {
            if (u < nb0) {
                float w = wlds[wv][u][head];
                a0 = fmaf(w, (float)hv_pre[u].x, a0);
                a1 = fmaf(w, (float)hv_pre[u].y, a1);
                a2 = fmaf(w, (float)hv_pre[u].z, a2);
                a3 = fmaf(w, (float)hv_pre[u].w, a3);
            }
        }
        int t = 8;
        for (; t + 8 <= deg; t += 8) {
            int sn[8];
            float w[8];
#pragma unroll
            for (int u = 0; u < 8; u++) {
                sn[u] = snlds[wv][t + u];
                w[u] = wlds[wv][t + u][head];
            }
            f16x4 hv[8];
#pragma unroll
            for (int u = 0; u < 8; u++)
                hv[u] = *(const f16x4*)(hb + (size_t)sn[u] * HD + lane * 4);
#pragma unroll
            for (int u = 0; u < 8; u++) {
                a0 = fmaf(w[u], (float)hv[u].x, a0);
                a1 = fmaf(w[u], (float)hv[u].y, a1);
                a2 = fmaf(w[u], (float)hv[u].z, a2);
                a3 = fmaf(w[u], (float)hv[u].w, a3);
            }
        }
        for (; t < deg; t++) {
            int sn = snlds[wv][t];
            float w = wlds[wv][t][head];
            f16x4 hv = *(const f16x4*)(hb + (size_t)sn * HD + lane * 4);
            a0 = fmaf(w, (float)hv.x, a0);
            a1 = fmaf(w, (float)hv.y, a1);
            a2 = fmaf(w, (float)hv.z, a2);
            a3 = fmaf(w, (float)hv.w, a3);
        }
    } else {
        for (int t = 0; t < deg; t++) {
            int sn = csr_src[rs + t];
            float e = el[(size_t)sn * 4 + head] + er_h;
            e = e > 0.f ? e : 0.2f * e;
            float w = __expf(e - m_h);
            f16x4 hv = *(const f16x4*)(hb + (size_t)sn * HD + lane * 4);
            a0 = fmaf(w, (float)hv.x, a0);
            a1 = fmaf(w, (float)hv.y, a1);
            a2 = fmaf(w, (float)hv.z, a2);
            a3 = fmaf(w, (float)hv.w, a3);
        }
    }
    float4 bv = *(const float4*)(bias + lane * 4);
    float4 o;
    o.x = selu_f(fmaf(a0, inv_den, bv.x));
    o.y = selu_f(fmaf(a1, inv_den, bv.y));
    o.z = selu_f(fmaf(a2, inv_den, bv.z));
    o.w = selu_f(fmaf(a3, inv_den, bv.w));

    if constexpr (OUT == 0) {
        f16x4 oh, ol;
        oh.x = (_Float16)o.x; ol.x = (_Float16)(o.x - (float)oh.x);
        oh.y = (_Float16)o.y; ol.y = (_Float16)(o.y - (float)oh.y);
        oh.z = (_Float16)o.z; ol.z = (_Float16)(o.z - (float)oh.z);
        oh.w = (_Float16)o.w; ol.w = (_Float16)(o.w - (float)oh.w);
        if (valid) {
            *(f16x4*)(xhi + (size_t)v * HD + lane * 4) = oh;
            *(f16x4*)(xlo + (size_t)v * HD + lane * 4) = ol;
        }
    } else {
        if (valid) *(float4*)(xf32 + (size_t)v * HD + lane * 4) = o;
        float4 sv = *(const float4*)(sw + lane * 4);
        float p = o.x * sv.x + o.y * sv.y + o.z * sv.z + o.w * sv.w;
#pragma unroll
        for (int off = 1; off < 64; off <<= 1) p += __shfl_xor(p, off, 64);
        if (lane == 0 && valid) wsc[v] = 1.f / (1.f + __expf(-(p + sb[0])));
    }
}

// ---------------- readout ----------------
__global__ __launch_bounds__(256) void readout_k(const float* __restrict__ x,
                                                 const float* __restrict__ wsc,
                                                 const int* __restrict__ gstart,
                                                 const float* __restrict__ fg,
                                                 float* __restrict__ y0) {
    int g = blockIdx.x;
    int f = threadIdx.x;
    int s = gstart[g], e = gstart[g + 1];
    float num = 0.f, den = 0.f;
#pragma unroll 4
    for (int n = s; n < e; n++) {
        float wn = wsc[n];
        num = fmaf(wn, x[(size_t)n * HD + f], num);
        den += wn;
    }
    float emb = num / fmaxf(den, 1e-9f);
    y0[(size_t)g * 272 + f] = emb;
    if (f < EXTRA) y0[(size_t)g * 272 + 256 + f] = fg[g * EXTRA + f];
}

__global__ __launch_bounds__(128) void mlp_k(const float* __restrict__ y0g,
                                             const float* __restrict__ lw1, const float* __restrict__ lb1,
                                             const float* __restrict__ lw2, const float* __restrict__ lb2,
                                             const float* __restrict__ lw3, const float* __restrict__ lb3,
                                             float* __restrict__ out) {
    __shared__ float y0s[272];
    __shared__ float y1s[128];
    int g = blockIdx.x, t = threadIdx.x;
    for (int i = t; i < 272; i += 128) y0s[i] = y0g[(size_t)g * 272 + i];
    __syncthreads();
    float acc = lb1[t];
    for (int k = 0; k < 272; k++) acc = fmaf(y0s[k], lw1[k * 128 + t], acc);
    y1s[t] = selu_f(acc);
    __syncthreads();
    if (t < 64) {
        float a2 = lb2[t];
        for (int k = 0; k < 128; k++) a2 = fmaf(y1s[k], lw2[k * 64 + t], a2);
        float v2 = selu_f(a2);
        float p = v2 * lw3[t];
#pragma unroll
        for (int off = 1; off < 64; off <<= 1) p += __shfl_xor(p, off, 64);
        if (t == 0) out[g] = p + lb3[0];
    }
}

extern "C" void kernel_launch(void* const* d_in, const int* in_sizes, int n_in,
                              void* d_out, int out_size, void* d_ws, size_t ws_size,
                              hipStream_t stream) {
    const int* src = (const int*)d_in[0];
    const int* dst = (const int*)d_in[1];
    const int* node_graph = (const int*)d_in[2];
    const float* feats_node = (const float*)d_in[3];
    const float* feats_graph = (const float*)d_in[4];
    const float* W1 = (const float*)d_in[5];
    const float* al1 = (const float*)d_in[6];
    const float* ar1 = (const float*)d_in[7];
    const float* bg1 = (const float*)d_in[8];
    const float* W2 = (const float*)d_in[9];
    const float* al2 = (const float*)d_in[10];
    const float* ar2 = (const float*)d_in[11];
    const float* bg2 = (const float*)d_in[12];
    const float* W3 = (const float*)d_in[13];
    const float* al3 = (const float*)d_in[14];
    const float* ar3 = (const float*)d_in[15];
    const float* bg3 = (const float*)d_in[16];
    const float* sw = (const float*)d_in[17];
    const float* sb = (const float*)d_in[18];
    const float* lw1 = (const float*)d_in[19];
    const float* lb1 = (const float*)d_in[20];
    const float* lw2 = (const float*)d_in[21];
    const float* lb2 = (const float*)d_in[22];
    const float* lw3 = (const float*)d_in[23];
    const float* lb3 = (const float*)d_in[24];
    float* out = (float*)d_out;

    char* ws = (char*)d_ws;
    size_t off = 0;
    auto alloc = [&](size_t bytes) -> char* {
        char* p = ws + off;
        off += (bytes + 255) & ~(size_t)255;
        return p;
    };
    _Float16* xhi = (_Float16*)alloc((size_t)N_NODES * HD * 2);
    _Float16* xlo = (_Float16*)alloc((size_t)N_NODES * HD * 2);
    float* xf32 = (float*)xhi;  // aliases xhi+xlo (disjoint lifetimes)
    _Float16* hhi = (_Float16*)alloc((size_t)N_NODES * HD * 2);
    _Float16* fhi = (_Float16*)alloc((size_t)N_NODES * F_IN * 2);
    _Float16* flo = (_Float16*)alloc((size_t)N_NODES * F_IN * 2);
    _Float16* W1hi = (_Float16*)alloc((size_t)F_IN * HD * 2);
    _Float16* W1lo = (_Float16*)alloc((size_t)F_IN * HD * 2);
    _Float16* W2hi = (_Float16*)alloc((size_t)HD * HD * 2);
    _Float16* W2lo = (_Float16*)alloc((size_t)HD * HD * 2);
    _Float16* W3hi = (_Float16*)alloc((size_t)HD * HD * 2);
    _Float16* W3lo = (_Float16*)alloc((size_t)HD * HD * 2);
    float* el = (float*)alloc((size_t)N_NODES * 4 * 4);
    float* er = (float*)alloc((size_t)N_NODES * 4 * 4);
    float* wsc = (float*)alloc((size_t)N_NODES * 4);
    float* y0 = (float*)alloc((size_t)N_GRAPHS * 272 * 4);
    int* hist = (int*)alloc((size_t)N_NODES * 4);
    int* row_ptr = (int*)alloc((size_t)(N_NODES + 1) * 4);
    int* cursor = (int*)alloc((size_t)N_NODES * 4);
    int* csr_src = (int*)alloc((size_t)N_EDGES * 4);
    int* gstart = (int*)alloc((size_t)(N_GRAPHS + 1) * 4);
    int* bsums = (int*)alloc(256 * 4);
    (void)ws_size; (void)in_sizes; (void)n_in; (void)out_size;

    hipMemsetAsync(hist, 0, (size_t)N_NODES * 4, stream);

    // CSR build (by dst)
    hist_k<<<(N_EDGES + 255) / 256, 256, 0, stream>>>(dst, hist);
    int nb = (N_NODES + SCAN_BLOCK - 1) / SCAN_BLOCK;
    scan1_k<<<nb, SCAN_BLOCK, 0, stream>>>(hist, row_ptr, bsums);
    scan2_k<<<1, 256, 0, stream>>>(bsums, nb);
    scan3_k<<<(N_NODES + 255) / 256, 256, 0, stream>>>(row_ptr, bsums, cursor);
    scatter_k<<<(N_EDGES + 255) / 256, 256, 0, stream>>>(src, dst, cursor, csr_src);
    gbound_k<<<3, 256, 0, stream>>>(node_graph, gstart);

    // splits
    split_cast_k<<<(N_NODES * F_IN / 4 + 255) / 256, 256, 0, stream>>>(feats_node, fhi, flo, N_NODES * F_IN / 4);
    tcast_split_k<<<(F_IN * HD + 255) / 256, 256, 0, stream>>>(W1, W1hi, W1lo, F_IN);
    tcast_split_k<<<(HD * HD + 255) / 256, 256, 0, stream>>>(W2, W2hi, W2lo, HD);
    tcast_split_k<<<(HD * HD + 255) / 256, 256, 0, stream>>>(W3, W3hi, W3lo, HD);

    dim3 ggrid(HD / 128, (N_NODES + 127) / 128);
    int nwb = (N_NODES + 3) / 4;

    // layer 1
    gemm_split_k<F_IN><<<ggrid, 256, 0, stream>>>(fhi, flo, W1hi, W1lo, al1, ar1, hhi, el, er, N_NODES);
    gat_aggregate_k<0><<<nwb, 256, 0, stream>>>(hhi, el, er, csr_src, row_ptr, bg1, xhi, xlo, nullptr, nullptr, nullptr, nullptr);
    // layer 2
    gemm_split_k<HD><<<ggrid, 256, 0, stream>>>(xhi, xlo, W2hi, W2lo, al2, ar2, hhi, el, er, N_NODES);
    gat_aggregate_k<0><<<nwb, 256, 0, stream>>>(hhi, el, er, csr_src, row_ptr, bg2, xhi, xlo, nullptr, nullptr, nullptr, nullptr);
    // layer 3 (fp32 out + fused sigmoid score)
    gemm_split_k<HD><<<ggrid, 256, 0, stream>>>(xhi, xlo, W3hi, W3lo, al3, ar3, hhi, el, er, N_NODES);
    gat_aggregate_k<1><<<nwb, 256, 0, stream>>>(hhi, el, er, csr_src, row_ptr, bg3, nullptr, nullptr, xf32, sw, sb, wsc);

    // readout + MLP
    readout_k<<<N_GRAPHS, 256, 0, stream>>>(xf32, wsc, gstart, feats_graph, y0);
    mlp_k<<<N_GRAPHS, 128, 0, stream>>>(y0, lw1, lb1, lw2, lb2, lw3, lb3, out);
}

// Round 12
// 941.250 us; speedup vs baseline: 1.0255x; 1.0255x over previous
//
#include <hip/hip_runtime.h>

#define N_NODES 100000
#define N_EDGES 1600000
#define N_GRAPHS 512
#define F_IN 64
#define HD 256
#define EXTRA 16
#define SCAN_BLOCK 512

typedef float f32x4 __attribute__((ext_vector_type(4)));
typedef _Float16 f16x4 __attribute__((ext_vector_type(4)));
typedef _Float16 f16x8 __attribute__((ext_vector_type(8)));

__device__ __forceinline__ float selu_f(float x) {
    const float a = 1.6732632423543772f, sc = 1.0507009873554805f;
    return x > 0.f ? sc * x : sc * a * (__expf(x) - 1.f);
}

// ---------------- CSR build ----------------
__global__ __launch_bounds__(256) void hist_k(const int* __restrict__ dst, int* __restrict__ hist) {
    int j = blockIdx.x * 256 + threadIdx.x;
    if (j < N_EDGES) atomicAdd(&hist[dst[j]], 1);
}

__global__ __launch_bounds__(SCAN_BLOCK) void scan1_k(const int* __restrict__ hist,
                                                      int* __restrict__ row_ptr,
                                                      int* __restrict__ bsums) {
    __shared__ int sm[SCAN_BLOCK];
    int t = threadIdx.x;
    int i = blockIdx.x * SCAN_BLOCK + t;
    int v = (i < N_NODES) ? hist[i] : 0;
    sm[t] = v;
    __syncthreads();
    for (int off = 1; off < SCAN_BLOCK; off <<= 1) {
        int add = (t >= off) ? sm[t - off] : 0;
        __syncthreads();
        sm[t] += add;
        __syncthreads();
    }
    if (i < N_NODES) row_ptr[i] = sm[t] - v;
    if (t == SCAN_BLOCK - 1) bsums[blockIdx.x] = sm[t];
}

__global__ __launch_bounds__(256) void scan2_k(int* __restrict__ bsums, int nb) {
    __shared__ int sm[256];
    int t = threadIdx.x;
    int v = (t < nb) ? bsums[t] : 0;
    sm[t] = v;
    __syncthreads();
    for (int off = 1; off < 256; off <<= 1) {
        int add = (t >= off) ? sm[t - off] : 0;
        __syncthreads();
        sm[t] += add;
        __syncthreads();
    }
    if (t < nb) bsums[t] = sm[t] - v;
}

__global__ __launch_bounds__(256) void scan3_k(int* __restrict__ row_ptr, const int* __restrict__ bsums,
                                               int* __restrict__ cursor) {
    int i = blockIdx.x * 256 + threadIdx.x;
    if (i < N_NODES) {
        int r = row_ptr[i] + bsums[i / SCAN_BLOCK];
        row_ptr[i] = r;
        cursor[i] = r;
    }
    if (i == 0) row_ptr[N_NODES] = N_EDGES;
}

__global__ __launch_bounds__(256) void scatter_k(const int* __restrict__ src,
                                                 const int* __restrict__ dst,
                                                 int* __restrict__ cursor,
                                                 int* __restrict__ csr_src) {
    int j = blockIdx.x * 256 + threadIdx.x;
    if (j < N_EDGES) {
        int r = atomicAdd(&cursor[dst[j]], 1);
        csr_src[r] = src[j];
    }
}

__global__ __launch_bounds__(256) void gbound_k(const int* __restrict__ node_graph, int* __restrict__ gstart) {
    int g = blockIdx.x * 256 + threadIdx.x;
    if (g > N_GRAPHS) return;
    int lo = 0, hi = N_NODES;
    while (lo < hi) {
        int mid = (lo + hi) >> 1;
        if (node_graph[mid] < g) lo = mid + 1; else hi = mid;
    }
    gstart[g] = lo;
}

// ---------------- splits/casts ----------------
__global__ __launch_bounds__(256) void tcast_split_k(const float* __restrict__ W,
                                                     _Float16* __restrict__ Wt_hi,
                                                     _Float16* __restrict__ Wt_lo, int K) {
    int idx = blockIdx.x * 256 + threadIdx.x;
    if (idx >= K * HD) return;
    int n = idx / K, k = idx - n * K;
    float w = W[(size_t)k * HD + n];
    _Float16 hi = (_Float16)w;
    _Float16 lo = (_Float16)(w - (float)hi);
    Wt_hi[idx] = hi;
    Wt_lo[idx] = lo;
}

__global__ __launch_bounds__(256) void split_cast_k(const float* __restrict__ in,
                                                    _Float16* __restrict__ hi,
                                                    _Float16* __restrict__ lo, int n4) {
    int i = blockIdx.x * 256 + threadIdx.x;
    if (i >= n4) return;
    float4 v = *(const float4*)(in + (size_t)i * 4);
    f16x4 h, l;
    h.x = (_Float16)v.x; l.x = (_Float16)(v.x - (float)h.x);
    h.y = (_Float16)v.y; l.y = (_Float16)(v.y - (float)h.y);
    h.z = (_Float16)v.z; l.z = (_Float16)(v.z - (float)h.z);
    h.w = (_Float16)v.w; l.w = (_Float16)(v.w - (float)h.w);
    *(f16x4*)(hi + (size_t)i * 4) = h;
    *(f16x4*)(lo + (size_t)i * 4) = l;
}

// ---------------- split-f16 MFMA GEMM: 64x128 tile, high occupancy ----------------
// 4 waves, each owns 64x32 (4 m-frags x 2 n-frags). ~33KB LDS, ~124 VGPR -> ~4 blocks/CU.
template <int K>
__global__ __launch_bounds__(256) void gemm_split_k(const _Float16* __restrict__ Ahi,
                                                    const _Float16* __restrict__ Alo,
                                                    const _Float16* __restrict__ Bt_hi,
                                                    const _Float16* __restrict__ Bt_lo,
                                                    const float* __restrict__ al,
                                                    const float* __restrict__ ar,
                                                    _Float16* __restrict__ Chi,
                                                    float* __restrict__ el,
                                                    float* __restrict__ er, int M) {
    const int BM = 64, BN = 128, LDP = 40;
    __shared__ _Float16 Ash[BM][LDP];
    __shared__ _Float16 Asl[BM][LDP];
    __shared__ _Float16 Bsh[BN][LDP];
    __shared__ _Float16 Bsl[BN][LDP];
    __shared__ float pl[4][64];
    __shared__ float pr[4][64];
    int tid = threadIdx.x;
    int w = tid >> 6, lane = tid & 63;
    int q = lane >> 4, l16 = lane & 15;
    int row0 = blockIdx.y * BM, col0 = blockIdx.x * BN;
    f32x4 acc[4][2] = {};

    // staging: A one f16x8 chunk/thread, B two chunks/thread
    int ar_ = tid >> 2, ao = (tid & 3) * 8;
    f16x8 rAh, rAl, rBh[2], rBl[2];

    auto load_tile = [&](int k0) {
        int gr = row0 + ar_;
        f16x8 vh = {}, vl = {};
        if (gr < M) {
            vh = *(const f16x8*)(Ahi + (size_t)gr * K + k0 + ao);
            vl = *(const f16x8*)(Alo + (size_t)gr * K + k0 + ao);
        }
        rAh = vh; rAl = vl;
#pragma unroll
        for (int c = 0; c < 2; c++) {
            int cc = tid + c * 256;
            int br = cc >> 2, bo = (cc & 3) * 8;
            int gb = col0 + br;
            rBh[c] = *(const f16x8*)(Bt_hi + (size_t)gb * K + k0 + bo);
            rBl[c] = *(const f16x8*)(Bt_lo + (size_t)gb * K + k0 + bo);
        }
    };
    auto store_tile = [&]() {
        *(f16x8*)&Ash[ar_][ao] = rAh;
        *(f16x8*)&Asl[ar_][ao] = rAl;
#pragma unroll
        for (int c = 0; c < 2; c++) {
            int cc = tid + c * 256;
            int br = cc >> 2, bo = (cc & 3) * 8;
            *(f16x8*)&Bsh[br][bo] = rBh[c];
            *(f16x8*)&Bsl[br][bo] = rBl[c];
        }
    };

    load_tile(0);
    store_tile();
    __syncthreads();

    for (int k0 = 0; k0 < K; k0 += 32) {
        bool more = (k0 + 32) < K;
        if (more) load_tile(k0 + 32);  // in flight during MFMA below

        f16x8 ah[4], alo2[4], bh[2], bl[2];
#pragma unroll
        for (int mf = 0; mf < 4; mf++) {
            int m = mf * 16 + l16;
            ah[mf] = *(const f16x8*)&Ash[m][q * 8];
            alo2[mf] = *(const f16x8*)&Asl[m][q * 8];
        }
#pragma unroll
        for (int nf = 0; nf < 2; nf++) {
            int n = w * 32 + nf * 16 + l16;
            bh[nf] = *(const f16x8*)&Bsh[n][q * 8];
            bl[nf] = *(const f16x8*)&Bsl[n][q * 8];
        }
#pragma unroll
        for (int mf = 0; mf < 4; mf++)
#pragma unroll
            for (int nf = 0; nf < 2; nf++) {
                acc[mf][nf] = __builtin_amdgcn_mfma_f32_16x16x32_f16(ah[mf], bh[nf], acc[mf][nf], 0, 0, 0);
                acc[mf][nf] = __builtin_amdgcn_mfma_f32_16x16x32_f16(ah[mf], bl[nf], acc[mf][nf], 0, 0, 0);
                acc[mf][nf] = __builtin_amdgcn_mfma_f32_16x16x32_f16(alo2[mf], bh[nf], acc[mf][nf], 0, 0, 0);
            }
        if (more) {
            __syncthreads();
            store_tile();
            __syncthreads();
        }
    }

    // epilogue: wave w covers cols col0+w*32.., i.e. half (w&1) of head (col0>>6)+(w>>1)
    const int hh = (col0 >> 6) + (w >> 1);
    float alv[2], arv[2];
#pragma unroll
    for (int nf = 0; nf < 2; nf++) {
        int d = (w & 1) * 32 + nf * 16 + l16;
        alv[nf] = al[hh * 64 + d];
        arv[nf] = ar[hh * 64 + d];
    }
#pragma unroll
    for (int mf = 0; mf < 4; mf++) {
#pragma unroll
        for (int i = 0; i < 4; i++) {
            int rl = mf * 16 + q * 4 + i;
            int r = row0 + rl;
            bool ok = r < M;
            float e_l = 0.f, e_r = 0.f;
#pragma unroll
            for (int nf = 0; nf < 2; nf++) {
                float v = acc[mf][nf][i];
                if (ok) Chi[(size_t)r * HD + col0 + w * 32 + nf * 16 + l16] = (_Float16)v;
                e_l = fmaf(v, alv[nf], e_l);
                e_r = fmaf(v, arv[nf], e_r);
            }
#pragma unroll
            for (int off = 1; off < 16; off <<= 1) {
                e_l += __shfl_xor(e_l, off, 64);
                e_r += __shfl_xor(e_r, off, 64);
            }
            if (l16 == 0) {
                pl[w][rl] = e_l;
                pr[w][rl] = e_r;
            }
        }
    }
    __syncthreads();
    // combine halves: heads (col0>>6)+0/+1
    int h2 = (tid >> 6) & 1, rr = tid & 63;
    int grow = row0 + rr;
    if (grow < M) {
        if (tid < 128) el[(size_t)grow * 4 + (col0 >> 6) + h2] = pl[2 * h2][rr] + pl[2 * h2 + 1][rr];
        else           er[(size_t)grow * 4 + (col0 >> 6) + h2] = pr[2 * h2][rr] + pr[2 * h2 + 1][rr];
    }
}

// ---------------- GAT aggregation (R9: barrier-free, 8-deep prefetch) ----------------
template <int OUT>
__global__ __launch_bounds__(256) void gat_aggregate_k(const _Float16* __restrict__ hb,
                                                       const float* __restrict__ el,
                                                       const float* __restrict__ er,
                                                       const int* __restrict__ csr_src,
                                                       const int* __restrict__ row_ptr,
                                                       const float* __restrict__ bias,
                                                       _Float16* __restrict__ xhi,
                                                       _Float16* __restrict__ xlo,
                                                       float* __restrict__ xf32,
                                                       const float* __restrict__ sw,
                                                       const float* __restrict__ sb,
                                                       float* __restrict__ wsc) {
    __shared__ float wlds[4][64][4];
    __shared__ int snlds[4][64];
    int wv = threadIdx.x >> 6;
    int lane = threadIdx.x & 63;
    int v = blockIdx.x * 4 + wv;
    bool valid = v < N_NODES;
    int vc = valid ? v : 0;
    int rs = row_ptr[vc];
    int deg = valid ? row_ptr[vc + 1] - rs : 0;
    float4 erv = make_float4(0.f, 0.f, 0.f, 0.f);
    if (valid) erv = *(const float4*)(er + (size_t)vc * 4);

    int head = lane >> 4;
    float inv_den = 1.f;
    float m_h = 0.f, er_h = 0.f;
    f16x4 hv_pre[8];
    int nb0 = 0;

    if (deg <= 64) {
        float e0 = -1e30f, e1 = -1e30f, e2 = -1e30f, e3 = -1e30f;
        int my_sn = 0;
        if (lane < deg) {
            my_sn = csr_src[rs + lane];
            float4 elv = *(const float4*)(el + (size_t)my_sn * 4);
            float t0 = elv.x + erv.x, t1 = elv.y + erv.y, t2 = elv.z + erv.z, t3 = elv.w + erv.w;
            e0 = t0 > 0.f ? t0 : 0.2f * t0;
            e1 = t1 > 0.f ? t1 : 0.2f * t1;
            e2 = t2 > 0.f ? t2 : 0.2f * t2;
            e3 = t3 > 0.f ? t3 : 0.2f * t3;
        }
        nb0 = deg < 8 ? deg : 8;
#pragma unroll
        for (int u = 0; u < 8; u++) {
            int snb = __shfl(my_sn, u, 64);
            if (u < nb0) hv_pre[u] = *(const f16x4*)(hb + (size_t)snb * HD + lane * 4);
        }
        float m0 = e0, m1 = e1, m2 = e2, m3 = e3;
        for (int off = 1; off < deg; off <<= 1) {
            m0 = fmaxf(m0, __shfl_xor(m0, off, 64));
            m1 = fmaxf(m1, __shfl_xor(m1, off, 64));
            m2 = fmaxf(m2, __shfl_xor(m2, off, 64));
            m3 = fmaxf(m3, __shfl_xor(m3, off, 64));
        }
        float p0 = 0.f, p1 = 0.f, p2 = 0.f, p3 = 0.f;
        if (lane < deg) {
            p0 = __expf(e0 - m0); p1 = __expf(e1 - m1);
            p2 = __expf(e2 - m2); p3 = __expf(e3 - m3);
        }
        float s0 = p0, s1 = p1, s2 = p2, s3 = p3;
        for (int off = 1; off < deg; off <<= 1) {
            s0 += __shfl_xor(s0, off, 64);
            s1 += __shfl_xor(s1, off, 64);
            s2 += __shfl_xor(s2, off, 64);
            s3 += __shfl_xor(s3, off, 64);
        }
        float d0 = __shfl(s0, 0, 64), d1 = __shfl(s1, 0, 64);
        float d2 = __shfl(s2, 0, 64), d3 = __shfl(s3, 0, 64);
        float dh = head == 0 ? d0 : head == 1 ? d1 : head == 2 ? d2 : d3;
        inv_den = 1.f / fmaxf(dh, 1e-9f);
        if (lane < deg) {
            wlds[wv][lane][0] = p0;
            wlds[wv][lane][1] = p1;
            wlds[wv][lane][2] = p2;
            wlds[wv][lane][3] = p3;
            snlds[wv][lane] = my_sn;
        }
        // no barrier: wave-private LDS slice
    } else {
        float m[4] = {-1e30f, -1e30f, -1e30f, -1e30f};
        float s[4] = {0.f, 0.f, 0.f, 0.f};
        for (int t = lane; t < deg; t += 64) {
            int sn = csr_src[rs + t];
            float4 elv = *(const float4*)(el + (size_t)sn * 4);
            float e[4];
            e[0] = elv.x + erv.x; e[1] = elv.y + erv.y; e[2] = elv.z + erv.z; e[3] = elv.w + erv.w;
#pragma unroll
            for (int hh = 0; hh < 4; hh++) {
                float ev = e[hh] > 0.f ? e[hh] : 0.2f * e[hh];
                float mn = fmaxf(m[hh], ev);
                s[hh] = s[hh] * __expf(m[hh] - mn) + __expf(ev - mn);
                m[hh] = mn;
            }
        }
#pragma unroll
        for (int off = 32; off >= 1; off >>= 1) {
#pragma unroll
            for (int hh = 0; hh < 4; hh++) {
                float mo = __shfl_xor(m[hh], off, 64);
                float so = __shfl_xor(s[hh], off, 64);
                float mn = fmaxf(m[hh], mo);
                s[hh] = s[hh] * __expf(m[hh] - mn) + so * __expf(mo - mn);
                m[hh] = mn;
            }
        }
        m_h = head == 0 ? m[0] : head == 1 ? m[1] : head == 2 ? m[2] : m[3];
        float dh = head == 0 ? s[0] : head == 1 ? s[1] : head == 2 ? s[2] : s[3];
        er_h = head == 0 ? erv.x : head == 1 ? erv.y : head == 2 ? erv.z : erv.w;
        inv_den = 1.f / fmaxf(dh, 1e-9f);
    }

    float a0 = 0.f, a1 = 0.f, a2 = 0.f, a3 = 0.f;
    if (deg <= 64) {
#pragma unroll
        for (int u = 0; u < 8; u++) {
            if (u < nb0) {
                float w = wlds[wv][u][head];
                a0 = fmaf(w, (float)hv_pre[u].x, a0);
                a1 = fmaf(w, (float)hv_pre[u].y, a1);
                a2 = fmaf(w, (float)hv_pre[u].z, a2);
                a3 = fmaf(w, (float)hv_pre[u].w, a3);
            }
        }
        int t = 8;
        for (; t + 8 <= deg; t += 8) {
            int sn[8];
            float w[8];
#pragma unroll
            for (int u = 0; u < 8; u++) {
                sn[u] = snlds[wv][t + u];
                w[u] = wlds[wv][t + u][head];
            }
            f16x4 hv[8];
#pragma unroll
            for (int u = 0; u < 8; u++)
                hv[u] = *(const f16x4*)(hb + (size_t)sn[u] * HD + lane * 4);
#pragma unroll
            for (int u = 0; u < 8; u++) {
                a0 = fmaf(w[u], (float)hv[u].x, a0);
                a1 = fmaf(w[u], (float)hv[u].y, a1);
                a2 = fmaf(w[u], (float)hv[u].z, a2);
                a3 = fmaf(w[u], (float)hv[u].w, a3);
            }
        }
        for (; t < deg; t++) {
            int sn = snlds[wv][t];
            float w = wlds[wv][t][head];
            f16x4 hv = *(const f16x4*)(hb + (size_t)sn * HD + lane * 4);
            a0 = fmaf(w, (float)hv.x, a0);
            a1 = fmaf(w, (float)hv.y, a1);
            a2 = fmaf(w, (float)hv.z, a2);
            a3 = fmaf(w, (float)hv.w, a3);
        }
    } else {
        for (int t = 0; t < deg; t++) {
            int sn = csr_src[rs + t];
            float e = el[(size_t)sn * 4 + head] + er_h;
            e = e > 0.f ? e : 0.2f * e;
            float w = __expf(e - m_h);
            f16x4 hv = *(const f16x4*)(hb + (size_t)sn * HD + lane * 4);
            a0 = fmaf(w, (float)hv.x, a0);
            a1 = fmaf(w, (float)hv.y, a1);
            a2 = fmaf(w, (float)hv.z, a2);
            a3 = fmaf(w, (float)hv.w, a3);
        }
    }
    float4 bv = *(const float4*)(bias + lane * 4);
    float4 o;
    o.x = selu_f(fmaf(a0, inv_den, bv.x));
    o.y = selu_f(fmaf(a1, inv_den, bv.y));
    o.z = selu_f(fmaf(a2, inv_den, bv.z));
    o.w = selu_f(fmaf(a3, inv_den, bv.w));

    if constexpr (OUT == 0) {
        f16x4 oh, ol;
        oh.x = (_Float16)o.x; ol.x = (_Float16)(o.x - (float)oh.x);
        oh.y = (_Float16)o.y; ol.y = (_Float16)(o.y - (float)oh.y);
        oh.z = (_Float16)o.z; ol.z = (_Float16)(o.z - (float)oh.z);
        oh.w = (_Float16)o.w; ol.w = (_Float16)(o.w - (float)oh.w);
        if (valid) {
            *(f16x4*)(xhi + (size_t)v * HD + lane * 4) = oh;
            *(f16x4*)(xlo + (size_t)v * HD + lane * 4) = ol;
        }
    } else {
        if (valid) *(float4*)(xf32 + (size_t)v * HD + lane * 4) = o;
        float4 sv = *(const float4*)(sw + lane * 4);
        float p = o.x * sv.x + o.y * sv.y + o.z * sv.z + o.w * sv.w;
#pragma unroll
        for (int off = 1; off < 64; off <<= 1) p += __shfl_xor(p, off, 64);
        if (lane == 0 && valid) wsc[v] = 1.f / (1.f + __expf(-(p + sb[0])));
    }
}

// ---------------- readout ----------------
__global__ __launch_bounds__(256) void readout_k(const float* __restrict__ x,
                                                 const float* __restrict__ wsc,
                                                 const int* __restrict__ gstart,
                                                 const float* __restrict__ fg,
                                                 float* __restrict__ y0) {
    int g = blockIdx.x;
    int f = threadIdx.x;
    int s = gstart[g], e = gstart[g + 1];
    float num = 0.f, den = 0.f;
#pragma unroll 4
    for (int n = s; n < e; n++) {
        float wn = wsc[n];
        num = fmaf(wn, x[(size_t)n * HD + f], num);
        den += wn;
    }
    float emb = num / fmaxf(den, 1e-9f);
    y0[(size_t)g * 272 + f] = emb;
    if (f < EXTRA) y0[(size_t)g * 272 + 256 + f] = fg[g * EXTRA + f];
}

__global__ __launch_bounds__(128) void mlp_k(const float* __restrict__ y0g,
                                             const float* __restrict__ lw1, const float* __restrict__ lb1,
                                             const float* __restrict__ lw2, const float* __restrict__ lb2,
                                             const float* __restrict__ lw3, const float* __restrict__ lb3,
                                             float* __restrict__ out) {
    __shared__ float y0s[272];
    __shared__ float y1s[128];
    int g = blockIdx.x, t = threadIdx.x;
    for (int i = t; i < 272; i += 128) y0s[i] = y0g[(size_t)g * 272 + i];
    __syncthreads();
    float acc = lb1[t];
    for (int k = 0; k < 272; k++) acc = fmaf(y0s[k], lw1[k * 128 + t], acc);
    y1s[t] = selu_f(acc);
    __syncthreads();
    if (t < 64) {
        float a2 = lb2[t];
        for (int k = 0; k < 128; k++) a2 = fmaf(y1s[k], lw2[k * 64 + t], a2);
        float v2 = selu_f(a2);
        float p = v2 * lw3[t];
#pragma unroll
        for (int off = 1; off < 64; off <<= 1) p += __shfl_xor(p, off, 64);
        if (t == 0) out[g] = p + lb3[0];
    }
}

extern "C" void kernel_launch(void* const* d_in, const int* in_sizes, int n_in,
                              void* d_out, int out_size, void* d_ws, size_t ws_size,
                              hipStream_t stream) {
    const int* src = (const int*)d_in[0];
    const int* dst = (const int*)d_in[1];
    const int* node_graph = (const int*)d_in[2];
    const float* feats_node = (const float*)d_in[3];
    const float* feats_graph = (const float*)d_in[4];
    const float* W1 = (const float*)d_in[5];
    const float* al1 = (const float*)d_in[6];
    const float* ar1 = (const float*)d_in[7];
    const float* bg1 = (const float*)d_in[8];
    const float* W2 = (const float*)d_in[9];
    const float* al2 = (const float*)d_in[10];
    const float* ar2 = (const float*)d_in[11];
    const float* bg2 = (const float*)d_in[12];
    const float* W3 = (const float*)d_in[13];
    const float* al3 = (const float*)d_in[14];
    const float* ar3 = (const float*)d_in[15];
    const float* bg3 = (const float*)d_in[16];
    const float* sw = (const float*)d_in[17];
    const float* sb = (const float*)d_in[18];
    const float* lw1 = (const float*)d_in[19];
    const float* lb1 = (const float*)d_in[20];
    const float* lw2 = (const float*)d_in[21];
    const float* lb2 = (const float*)d_in[22];
    const float* lw3 = (const float*)d_in[23];
    const float* lb3 = (const float*)d_in[24];
    float* out = (float*)d_out;

    char* ws = (char*)d_ws;
    size_t off = 0;
    auto alloc = [&](size_t bytes) -> char* {
        char* p = ws + off;
        off += (bytes + 255) & ~(size_t)255;
        return p;
    };
    _Float16* xhi = (_Float16*)alloc((size_t)N_NODES * HD * 2);
    _Float16* xlo = (_Float16*)alloc((size_t)N_NODES * HD * 2);
    float* xf32 = (float*)xhi;  // aliases xhi+xlo (disjoint lifetimes)
    _Float16* hhi = (_Float16*)alloc((size_t)N_NODES * HD * 2);
    _Float16* fhi = (_Float16*)alloc((size_t)N_NODES * F_IN * 2);
    _Float16* flo = (_Float16*)alloc((size_t)N_NODES * F_IN * 2);
    _Float16* W1hi = (_Float16*)alloc((size_t)F_IN * HD * 2);
    _Float16* W1lo = (_Float16*)alloc((size_t)F_IN * HD * 2);
    _Float16* W2hi = (_Float16*)alloc((size_t)HD * HD * 2);
    _Float16* W2lo = (_Float16*)alloc((size_t)HD * HD * 2);
    _Float16* W3hi = (_Float16*)alloc((size_t)HD * HD * 2);
    _Float16* W3lo = (_Float16*)alloc((size_t)HD * HD * 2);
    float* el = (float*)alloc((size_t)N_NODES * 4 * 4);
    float* er = (float*)alloc((size_t)N_NODES * 4 * 4);
    float* wsc = (float*)alloc((size_t)N_NODES * 4);
    float* y0 = (float*)alloc((size_t)N_GRAPHS * 272 * 4);
    int* hist = (int*)alloc((size_t)N_NODES * 4);
    int* row_ptr = (int*)alloc((size_t)(N_NODES + 1) * 4);
    int* cursor = (int*)alloc((size_t)N_NODES * 4);
    int* csr_src = (int*)alloc((size_t)N_EDGES * 4);
    int* gstart = (int*)alloc((size_t)(N_GRAPHS + 1) * 4);
    int* bsums = (int*)alloc(256 * 4);
    (void)ws_size; (void)in_sizes; (void)n_in; (void)out_size;

    hipMemsetAsync(hist, 0, (size_t)N_NODES * 4, stream);

    // CSR build (by dst)
    hist_k<<<(N_EDGES + 255) / 256, 256, 0, stream>>>(dst, hist);
    int nb = (N_NODES + SCAN_BLOCK - 1) / SCAN_BLOCK;
    scan1_k<<<nb, SCAN_BLOCK, 0, stream>>>(hist, row_ptr, bsums);
    scan2_k<<<1, 256, 0, stream>>>(bsums, nb);
    scan3_k<<<(N_NODES + 255) / 256, 256, 0, stream>>>(row_ptr, bsums, cursor);
    scatter_k<<<(N_EDGES + 255) / 256, 256, 0, stream>>>(src, dst, cursor, csr_src);
    gbound_k<<<3, 256, 0, stream>>>(node_graph, gstart);

    // splits
    split_cast_k<<<(N_NODES * F_IN / 4 + 255) / 256, 256, 0, stream>>>(feats_node, fhi, flo, N_NODES * F_IN / 4);
    tcast_split_k<<<(F_IN * HD + 255) / 256, 256, 0, stream>>>(W1, W1hi, W1lo, F_IN);
    tcast_split_k<<<(HD * HD + 255) / 256, 256, 0, stream>>>(W2, W2hi, W2lo, HD);
    tcast_split_k<<<(HD * HD + 255) / 256, 256, 0, stream>>>(W3, W3hi, W3lo, HD);

    dim3 ggrid(HD / 128, (N_NODES + 63) / 64);
    int nwb = (N_NODES + 3) / 4;

    // layer 1
    gemm_split_k<F_IN><<<ggrid, 256, 0, stream>>>(fhi, flo, W1hi, W1lo, al1, ar1, hhi, el, er, N_NODES);
    gat_aggregate_k<0><<<nwb, 256, 0, stream>>>(hhi, el, er, csr_src, row_ptr, bg1, xhi, xlo, nullptr, nullptr, nullptr, nullptr);
    // layer 2
    gemm_split_k<HD><<<ggrid, 256, 0, stream>>>(xhi, xlo, W2hi, W2lo, al2, ar2, hhi, el, er, N_NODES);
    gat_aggregate_k<0><<<nwb, 256, 0, stream>>>(hhi, el, er, csr_src, row_ptr, bg2, xhi, xlo, nullptr, nullptr, nullptr, nullptr);
    // layer 3 (fp32 out + fused sigmoid score)
    gemm_split_k<HD><<<ggrid, 256, 0, stream>>>(xhi, xlo, W3hi, W3lo, al3, ar3, hhi, el, er, N_NODES);
    gat_aggregate_k<1><<<nwb, 256, 0, stream>>>(hhi, el, er, csr_src, row_ptr, bg3, nullptr, nullptr, xf32, sw, sb, wsc);

    // readout + MLP
    readout_k<<<N_GRAPHS, 256, 0, stream>>>(xf32, wsc, gstart, feats_graph, y0);
    mlp_k<<<N_GRAPHS, 128, 0, stream>>>(y0, lw1, lb1, lw2, lb2, lw3, lb3, out);
}

// Round 13
// 932.044 us; speedup vs baseline: 1.0356x; 1.0099x over previous
//
#include <hip/hip_runtime.h>

#define N_NODES 100000
#define N_EDGES 1600000
#define N_GRAPHS 512
#define F_IN 64
#define HD 256
#define EXTRA 16
#define SCAN_BLOCK 512

typedef float f32x4 __attribute__((ext_vector_type(4)));
typedef _Float16 f16x4 __attribute__((ext_vector_type(4)));
typedef _Float16 f16x8 __attribute__((ext_vector_type(8)));

__device__ __forceinline__ float selu_f(float x) {
    const float a = 1.6732632423543772f, sc = 1.0507009873554805f;
    return x > 0.f ? sc * x : sc * a * (__expf(x) - 1.f);
}

// ---------------- CSR build ----------------
__global__ __launch_bounds__(256) void hist_k(const int* __restrict__ dst, int* __restrict__ hist) {
    int j = blockIdx.x * 256 + threadIdx.x;
    if (j < N_EDGES) atomicAdd(&hist[dst[j]], 1);
}

__global__ __launch_bounds__(SCAN_BLOCK) void scan1_k(const int* __restrict__ hist,
                                                      int* __restrict__ row_ptr,
                                                      int* __restrict__ bsums) {
    __shared__ int sm[SCAN_BLOCK];
    int t = threadIdx.x;
    int i = blockIdx.x * SCAN_BLOCK + t;
    int v = (i < N_NODES) ? hist[i] : 0;
    sm[t] = v;
    __syncthreads();
    for (int off = 1; off < SCAN_BLOCK; off <<= 1) {
        int add = (t >= off) ? sm[t - off] : 0;
        __syncthreads();
        sm[t] += add;
        __syncthreads();
    }
    if (i < N_NODES) row_ptr[i] = sm[t] - v;
    if (t == SCAN_BLOCK - 1) bsums[blockIdx.x] = sm[t];
}

__global__ __launch_bounds__(256) void scan2_k(int* __restrict__ bsums, int nb) {
    __shared__ int sm[256];
    int t = threadIdx.x;
    int v = (t < nb) ? bsums[t] : 0;
    sm[t] = v;
    __syncthreads();
    for (int off = 1; off < 256; off <<= 1) {
        int add = (t >= off) ? sm[t - off] : 0;
        __syncthreads();
        sm[t] += add;
        __syncthreads();
    }
    if (t < nb) bsums[t] = sm[t] - v;
}

__global__ __launch_bounds__(256) void scan3_k(int* __restrict__ row_ptr, const int* __restrict__ bsums,
                                               int* __restrict__ cursor) {
    int i = blockIdx.x * 256 + threadIdx.x;
    if (i < N_NODES) {
        int r = row_ptr[i] + bsums[i / SCAN_BLOCK];
        row_ptr[i] = r;
        cursor[i] = r;
    }
    if (i == 0) row_ptr[N_NODES] = N_EDGES;
}

__global__ __launch_bounds__(256) void scatter_k(const int* __restrict__ src,
                                                 const int* __restrict__ dst,
                                                 int* __restrict__ cursor,
                                                 int* __restrict__ csr_src) {
    int j = blockIdx.x * 256 + threadIdx.x;
    if (j < N_EDGES) {
        int r = atomicAdd(&cursor[dst[j]], 1);
        csr_src[r] = src[j];
    }
}

__global__ __launch_bounds__(256) void gbound_k(const int* __restrict__ node_graph, int* __restrict__ gstart) {
    int g = blockIdx.x * 256 + threadIdx.x;
    if (g > N_GRAPHS) return;
    int lo = 0, hi = N_NODES;
    while (lo < hi) {
        int mid = (lo + hi) >> 1;
        if (node_graph[mid] < g) lo = mid + 1; else hi = mid;
    }
    gstart[g] = lo;
}

// ---------------- weight split: W[k][n] fp32 -> Wt_hi/Wt_lo [n][k] f16 ----------------
__global__ __launch_bounds__(256) void tcast_split_k(const float* __restrict__ W,
                                                     _Float16* __restrict__ Wt_hi,
                                                     _Float16* __restrict__ Wt_lo, int K) {
    int idx = blockIdx.x * 256 + threadIdx.x;
    if (idx >= K * HD) return;
    int n = idx / K, k = idx - n * K;
    float w = W[(size_t)k * HD + n];
    _Float16 hi = (_Float16)w;
    _Float16 lo = (_Float16)(w - (float)hi);
    Wt_hi[idx] = hi;
    Wt_lo[idx] = lo;
}

// ---------------- split-f16 MFMA GEMM: 64x128 tile, LDS-staged coalesced C writes ----------------
// 4 waves, each owns 64x32 (4 m-frags x 2 n-frags). F32A: A is fp32, split inline (layer 1).
template <int K, bool F32A>
__global__ __launch_bounds__(256) void gemm_split_k(const void* __restrict__ Aptr,
                                                    const _Float16* __restrict__ Alo_p,
                                                    const _Float16* __restrict__ Bt_hi,
                                                    const _Float16* __restrict__ Bt_lo,
                                                    const float* __restrict__ al,
                                                    const float* __restrict__ ar,
                                                    _Float16* __restrict__ Chi,
                                                    float* __restrict__ el,
                                                    float* __restrict__ er, int M) {
    const int BM = 64, BN = 128, LDP = 40;
    __shared__ union {
        struct {
            _Float16 Ash[BM][LDP];
            _Float16 Asl[BM][LDP];
            _Float16 Bsh[BN][LDP];
            _Float16 Bsl[BN][LDP];
        } s;
        _Float16 ctile[BM][BN];
    } u;
    __shared__ float pl[4][64];
    __shared__ float pr[4][64];
    _Float16 (&Ash)[BM][LDP] = u.s.Ash;
    _Float16 (&Asl)[BM][LDP] = u.s.Asl;
    _Float16 (&Bsh)[BN][LDP] = u.s.Bsh;
    _Float16 (&Bsl)[BN][LDP] = u.s.Bsl;

    int tid = threadIdx.x;
    int w = tid >> 6, lane = tid & 63;
    int q = lane >> 4, l16 = lane & 15;
    int row0 = blockIdx.y * BM, col0 = blockIdx.x * BN;
    f32x4 acc[4][2] = {};

    int ar_ = tid >> 2, ao = (tid & 3) * 8;
    f16x8 rAh, rAl, rBh[2], rBl[2];

    auto load_tile = [&](int k0) {
        int gr = row0 + ar_;
        if constexpr (F32A) {
            const float* A32 = (const float*)Aptr;
            float vv[8] = {};
            if (gr < M) {
                float4 va = *(const float4*)(A32 + (size_t)gr * K + k0 + ao);
                float4 vb = *(const float4*)(A32 + (size_t)gr * K + k0 + ao + 4);
                vv[0] = va.x; vv[1] = va.y; vv[2] = va.z; vv[3] = va.w;
                vv[4] = vb.x; vv[5] = vb.y; vv[6] = vb.z; vv[7] = vb.w;
            }
            f16x8 h, l;
#pragma unroll
            for (int i = 0; i < 8; i++) {
                h[i] = (_Float16)vv[i];
                l[i] = (_Float16)(vv[i] - (float)h[i]);
            }
            rAh = h; rAl = l;
        } else {
            const _Float16* Ahi = (const _Float16*)Aptr;
            f16x8 vh = {}, vl = {};
            if (gr < M) {
                vh = *(const f16x8*)(Ahi + (size_t)gr * K + k0 + ao);
                vl = *(const f16x8*)(Alo_p + (size_t)gr * K + k0 + ao);
            }
            rAh = vh; rAl = vl;
        }
#pragma unroll
        for (int c = 0; c < 2; c++) {
            int cc = tid + c * 256;
            int br = cc >> 2, bo = (cc & 3) * 8;
            int gb = col0 + br;
            rBh[c] = *(const f16x8*)(Bt_hi + (size_t)gb * K + k0 + bo);
            rBl[c] = *(const f16x8*)(Bt_lo + (size_t)gb * K + k0 + bo);
        }
    };
    auto store_tile = [&]() {
        *(f16x8*)&Ash[ar_][ao] = rAh;
        *(f16x8*)&Asl[ar_][ao] = rAl;
#pragma unroll
        for (int c = 0; c < 2; c++) {
            int cc = tid + c * 256;
            int br = cc >> 2, bo = (cc & 3) * 8;
            *(f16x8*)&Bsh[br][bo] = rBh[c];
            *(f16x8*)&Bsl[br][bo] = rBl[c];
        }
    };

    load_tile(0);
    store_tile();
    __syncthreads();

    for (int k0 = 0; k0 < K; k0 += 32) {
        bool more = (k0 + 32) < K;
        if (more) load_tile(k0 + 32);

        f16x8 ah[4], alo2[4], bh[2], bl[2];
#pragma unroll
        for (int mf = 0; mf < 4; mf++) {
            int m = mf * 16 + l16;
            ah[mf] = *(const f16x8*)&Ash[m][q * 8];
            alo2[mf] = *(const f16x8*)&Asl[m][q * 8];
        }
#pragma unroll
        for (int nf = 0; nf < 2; nf++) {
            int n = w * 32 + nf * 16 + l16;
            bh[nf] = *(const f16x8*)&Bsh[n][q * 8];
            bl[nf] = *(const f16x8*)&Bsl[n][q * 8];
        }
#pragma unroll
        for (int mf = 0; mf < 4; mf++)
#pragma unroll
            for (int nf = 0; nf < 2; nf++) {
                acc[mf][nf] = __builtin_amdgcn_mfma_f32_16x16x32_f16(ah[mf], bh[nf], acc[mf][nf], 0, 0, 0);
                acc[mf][nf] = __builtin_amdgcn_mfma_f32_16x16x32_f16(ah[mf], bl[nf], acc[mf][nf], 0, 0, 0);
                acc[mf][nf] = __builtin_amdgcn_mfma_f32_16x16x32_f16(alo2[mf], bh[nf], acc[mf][nf], 0, 0, 0);
            }
        if (more) {
            __syncthreads();
            store_tile();
            __syncthreads();
        }
    }

    // all waves done reading frags before LDS is repurposed as ctile
    __syncthreads();

    // epilogue: wave w covers cols col0+w*32.., i.e. half (w&1) of head (col0>>6)+(w>>1)
    const int hh = (col0 >> 6) + (w >> 1);
    float alv[2], arv[2];
#pragma unroll
    for (int nf = 0; nf < 2; nf++) {
        int d = (w & 1) * 32 + nf * 16 + l16;
        alv[nf] = al[hh * 64 + d];
        arv[nf] = ar[hh * 64 + d];
    }
#pragma unroll
    for (int mf = 0; mf < 4; mf++) {
#pragma unroll
        for (int i = 0; i < 4; i++) {
            int rl = mf * 16 + q * 4 + i;
            float e_l = 0.f, e_r = 0.f;
#pragma unroll
            for (int nf = 0; nf < 2; nf++) {
                float v = acc[mf][nf][i];
                u.ctile[rl][w * 32 + nf * 16 + l16] = (_Float16)v;
                e_l = fmaf(v, alv[nf], e_l);
                e_r = fmaf(v, arv[nf], e_r);
            }
#pragma unroll
            for (int off = 1; off < 16; off <<= 1) {
                e_l += __shfl_xor(e_l, off, 64);
                e_r += __shfl_xor(e_r, off, 64);
            }
            if (l16 == 0) {
                pl[w][rl] = e_l;
                pr[w][rl] = e_r;
            }
        }
    }
    __syncthreads();
    // coalesced Chi copy: 16B chunks, 256B row segments
#pragma unroll
    for (int j = 0; j < 4; j++) {
        int c = tid + j * 256;
        int rr2 = c >> 4, co = (c & 15) * 8;
        int gr = row0 + rr2;
        if (gr < M)
            *(f16x8*)(Chi + (size_t)gr * HD + col0 + co) = *(const f16x8*)&u.ctile[rr2][co];
    }
    // combine halves: heads (col0>>6)+0/+1
    int h2 = (tid >> 6) & 1, rr = tid & 63;
    int grow = row0 + rr;
    if (grow < M) {
        if (tid < 128) el[(size_t)grow * 4 + (col0 >> 6) + h2] = pl[2 * h2][rr] + pl[2 * h2 + 1][rr];
        else           er[(size_t)grow * 4 + (col0 >> 6) + h2] = pr[2 * h2][rr] + pr[2 * h2 + 1][rr];
    }
}

// ---------------- GAT aggregation (R9: barrier-free, 8-deep prefetch) ----------------
template <int OUT>
__global__ __launch_bounds__(256) void gat_aggregate_k(const _Float16* __restrict__ hb,
                                                       const float* __restrict__ el,
                                                       const float* __restrict__ er,
                                                       const int* __restrict__ csr_src,
                                                       const int* __restrict__ row_ptr,
                                                       const float* __restrict__ bias,
                                                       _Float16* __restrict__ xhi,
                                                       _Float16* __restrict__ xlo,
                                                       float* __restrict__ xf32,
                                                       const float* __restrict__ sw,
                                                       const float* __restrict__ sb,
                                                       float* __restrict__ wsc) {
    __shared__ float wlds[4][64][4];
    __shared__ int snlds[4][64];
    int wv = threadIdx.x >> 6;
    int lane = threadIdx.x & 63;
    int v = blockIdx.x * 4 + wv;
    bool valid = v < N_NODES;
    int vc = valid ? v : 0;
    int rs = row_ptr[vc];
    int deg = valid ? row_ptr[vc + 1] - rs : 0;
    float4 erv = make_float4(0.f, 0.f, 0.f, 0.f);
    if (valid) erv = *(const float4*)(er + (size_t)vc * 4);

    int head = lane >> 4;
    float inv_den = 1.f;
    float m_h = 0.f, er_h = 0.f;
    f16x4 hv_pre[8];
    int nb0 = 0;

    if (deg <= 64) {
        float e0 = -1e30f, e1 = -1e30f, e2 = -1e30f, e3 = -1e30f;
        int my_sn = 0;
        if (lane < deg) {
            my_sn = csr_src[rs + lane];
            float4 elv = *(const float4*)(el + (size_t)my_sn * 4);
            float t0 = elv.x + erv.x, t1 = elv.y + erv.y, t2 = elv.z + erv.z, t3 = elv.w + erv.w;
            e0 = t0 > 0.f ? t0 : 0.2f * t0;
            e1 = t1 > 0.f ? t1 : 0.2f * t1;
            e2 = t2 > 0.f ? t2 : 0.2f * t2;
            e3 = t3 > 0.f ? t3 : 0.2f * t3;
        }
        nb0 = deg < 8 ? deg : 8;
#pragma unroll
        for (int u = 0; u < 8; u++) {
            int snb = __shfl(my_sn, u, 64);
            if (u < nb0) hv_pre[u] = *(const f16x4*)(hb + (size_t)snb * HD + lane * 4);
        }
        float m0 = e0, m1 = e1, m2 = e2, m3 = e3;
        for (int off = 1; off < deg; off <<= 1) {
            m0 = fmaxf(m0, __shfl_xor(m0, off, 64));
            m1 = fmaxf(m1, __shfl_xor(m1, off, 64));
            m2 = fmaxf(m2, __shfl_xor(m2, off, 64));
            m3 = fmaxf(m3, __shfl_xor(m3, off, 64));
        }
        float p0 = 0.f, p1 = 0.f, p2 = 0.f, p3 = 0.f;
        if (lane < deg) {
            p0 = __expf(e0 - m0); p1 = __expf(e1 - m1);
            p2 = __expf(e2 - m2); p3 = __expf(e3 - m3);
        }
        float s0 = p0, s1 = p1, s2 = p2, s3 = p3;
        for (int off = 1; off < deg; off <<= 1) {
            s0 += __shfl_xor(s0, off, 64);
            s1 += __shfl_xor(s1, off, 64);
            s2 += __shfl_xor(s2, off, 64);
            s3 += __shfl_xor(s3, off, 64);
        }
        float d0 = __shfl(s0, 0, 64), d1 = __shfl(s1, 0, 64);
        float d2 = __shfl(s2, 0, 64), d3 = __shfl(s3, 0, 64);
        float dh = head == 0 ? d0 : head == 1 ? d1 : head == 2 ? d2 : d3;
        inv_den = 1.f / fmaxf(dh, 1e-9f);
        if (lane < deg) {
            wlds[wv][lane][0] = p0;
            wlds[wv][lane][1] = p1;
            wlds[wv][lane][2] = p2;
            wlds[wv][lane][3] = p3;
            snlds[wv][lane] = my_sn;
        }
        // no barrier: wave-private LDS slice
    } else {
        float m[4] = {-1e30f, -1e30f, -1e30f, -1e30f};
        float s[4] = {0.f, 0.f, 0.f, 0.f};
        for (int t = lane; t < deg; t += 64) {
            int sn = csr_src[rs + t];
            float4 elv = *(const float4*)(el + (size_t)sn * 4);
            float e[4];
            e[0] = elv.x + erv.x; e[1] = elv.y + erv.y; e[2] = elv.z + erv.z; e[3] = elv.w + erv.w;
#pragma unroll
            for (int hh = 0; hh < 4; hh++) {
                float ev = e[hh] > 0.f ? e[hh] : 0.2f * e[hh];
                float mn = fmaxf(m[hh], ev);
                s[hh] = s[hh] * __expf(m[hh] - mn) + __expf(ev - mn);
                m[hh] = mn;
            }
        }
#pragma unroll
        for (int off = 32; off >= 1; off >>= 1) {
#pragma unroll
            for (int hh = 0; hh < 4; hh++) {
                float mo = __shfl_xor(m[hh], off, 64);
                float so = __shfl_xor(s[hh], off, 64);
                float mn = fmaxf(m[hh], mo);
                s[hh] = s[hh] * __expf(m[hh] - mn) + so * __expf(mo - mn);
                m[hh] = mn;
            }
        }
        m_h = head == 0 ? m[0] : head == 1 ? m[1] : head == 2 ? m[2] : m[3];
        float dh = head == 0 ? s[0] : head == 1 ? s[1] : head == 2 ? s[2] : s[3];
        er_h = head == 0 ? erv.x : head == 1 ? erv.y : head == 2 ? erv.z : erv.w;
        inv_den = 1.f / fmaxf(dh, 1e-9f);
    }

    float a0 = 0.f, a1 = 0.f, a2 = 0.f, a3 = 0.f;
    if (deg <= 64) {
#pragma unroll
        for (int u = 0; u < 8; u++) {
            if (u < nb0) {
                float w = wlds[wv][u][head];
                a0 = fmaf(w, (float)hv_pre[u].x, a0);
                a1 = fmaf(w, (float)hv_pre[u].y, a1);
                a2 = fmaf(w, (float)hv_pre[u].z, a2);
                a3 = fmaf(w, (float)hv_pre[u].w, a3);
            }
        }
        int t = 8;
        for (; t + 8 <= deg; t += 8) {
            int sn[8];
            float w[8];
#pragma unroll
            for (int u = 0; u < 8; u++) {
                sn[u] = snlds[wv][t + u];
                w[u] = wlds[wv][t + u][head];
            }
            f16x4 hv[8];
#pragma unroll
            for (int u = 0; u < 8; u++)
                hv[u] = *(const f16x4*)(hb + (size_t)sn[u] * HD + lane * 4);
#pragma unroll
            for (int u = 0; u < 8; u++) {
                a0 = fmaf(w[u], (float)hv[u].x, a0);
                a1 = fmaf(w[u], (float)hv[u].y, a1);
                a2 = fmaf(w[u], (float)hv[u].z, a2);
                a3 = fmaf(w[u], (float)hv[u].w, a3);
            }
        }
        for (; t < deg; t++) {
            int sn = snlds[wv][t];
            float w = wlds[wv][t][head];
            f16x4 hv = *(const f16x4*)(hb + (size_t)sn * HD + lane * 4);
            a0 = fmaf(w, (float)hv.x, a0);
            a1 = fmaf(w, (float)hv.y, a1);
            a2 = fmaf(w, (float)hv.z, a2);
            a3 = fmaf(w, (float)hv.w, a3);
        }
    } else {
        for (int t = 0; t < deg; t++) {
            int sn = csr_src[rs + t];
            float e = el[(size_t)sn * 4 + head] + er_h;
            e = e > 0.f ? e : 0.2f * e;
            float w = __expf(e - m_h);
            f16x4 hv = *(const f16x4*)(hb + (size_t)sn * HD + lane * 4);
            a0 = fmaf(w, (float)hv.x, a0);
            a1 = fmaf(w, (float)hv.y, a1);
            a2 = fmaf(w, (float)hv.z, a2);
            a3 = fmaf(w, (float)hv.w, a3);
        }
    }
    float4 bv = *(const float4*)(bias + lane * 4);
    float4 o;
    o.x = selu_f(fmaf(a0, inv_den, bv.x));
    o.y = selu_f(fmaf(a1, inv_den, bv.y));
    o.z = selu_f(fmaf(a2, inv_den, bv.z));
    o.w = selu_f(fmaf(a3, inv_den, bv.w));

    if constexpr (OUT == 0) {
        f16x4 oh, ol;
        oh.x = (_Float16)o.x; ol.x = (_Float16)(o.x - (float)oh.x);
        oh.y = (_Float16)o.y; ol.y = (_Float16)(o.y - (float)oh.y);
        oh.z = (_Float16)o.z; ol.z = (_Float16)(o.z - (float)oh.z);
        oh.w = (_Float16)o.w; ol.w = (_Float16)(o.w - (float)oh.w);
        if (valid) {
            *(f16x4*)(xhi + (size_t)v * HD + lane * 4) = oh;
            *(f16x4*)(xlo + (size_t)v * HD + lane * 4) = ol;
        }
    } else {
        if (valid) *(float4*)(xf32 + (size_t)v * HD + lane * 4) = o;
        float4 sv = *(const float4*)(sw + lane * 4);
        float p = o.x * sv.x + o.y * sv.y + o.z * sv.z + o.w * sv.w;
#pragma unroll
        for (int off = 1; off < 64; off <<= 1) p += __shfl_xor(p, off, 64);
        if (lane == 0 && valid) wsc[v] = 1.f / (1.f + __expf(-(p + sb[0])));
    }
}

// ---------------- readout ----------------
__global__ __launch_bounds__(256) void readout_k(const float* __restrict__ x,
                                                 const float* __restrict__ wsc,
                                                 const int* __restrict__ gstart,
                                                 const float* __restrict__ fg,
                                                 float* __restrict__ y0) {
    int g = blockIdx.x;
    int f = threadIdx.x;
    int s = gstart[g], e = gstart[g + 1];
    float num = 0.f, den = 0.f;
#pragma unroll 4
    for (int n = s; n < e; n++) {
        float wn = wsc[n];
        num = fmaf(wn, x[(size_t)n * HD + f], num);
        den += wn;
    }
    float emb = num / fmaxf(den, 1e-9f);
    y0[(size_t)g * 272 + f] = emb;
    if (f < EXTRA) y0[(size_t)g * 272 + 256 + f] = fg[g * EXTRA + f];
}

__global__ __launch_bounds__(128) void mlp_k(const float* __restrict__ y0g,
                                             const float* __restrict__ lw1, const float* __restrict__ lb1,
                                             const float* __restrict__ lw2, const float* __restrict__ lb2,
                                             const float* __restrict__ lw3, const float* __restrict__ lb3,
                                             float* __restrict__ out) {
    __shared__ float y0s[272];
    __shared__ float y1s[128];
    int g = blockIdx.x, t = threadIdx.x;
    for (int i = t; i < 272; i += 128) y0s[i] = y0g[(size_t)g * 272 + i];
    __syncthreads();
    float acc = lb1[t];
    for (int k = 0; k < 272; k++) acc = fmaf(y0s[k], lw1[k * 128 + t], acc);
    y1s[t] = selu_f(acc);
    __syncthreads();
    if (t < 64) {
        float a2 = lb2[t];
        for (int k = 0; k < 128; k++) a2 = fmaf(y1s[k], lw2[k * 64 + t], a2);
        float v2 = selu_f(a2);
        float p = v2 * lw3[t];
#pragma unroll
        for (int off = 1; off < 64; off <<= 1) p += __shfl_xor(p, off, 64);
        if (t == 0) out[g] = p + lb3[0];
    }
}

extern "C" void kernel_launch(void* const* d_in, const int* in_sizes, int n_in,
                              void* d_out, int out_size, void* d_ws, size_t ws_size,
                              hipStream_t stream) {
    const int* src = (const int*)d_in[0];
    const int* dst = (const int*)d_in[1];
    const int* node_graph = (const int*)d_in[2];
    const float* feats_node = (const float*)d_in[3];
    const float* feats_graph = (const float*)d_in[4];
    const float* W1 = (const float*)d_in[5];
    const float* al1 = (const float*)d_in[6];
    const float* ar1 = (const float*)d_in[7];
    const float* bg1 = (const float*)d_in[8];
    const float* W2 = (const float*)d_in[9];
    const float* al2 = (const float*)d_in[10];
    const float* ar2 = (const float*)d_in[11];
    const float* bg2 = (const float*)d_in[12];
    const float* W3 = (const float*)d_in[13];
    const float* al3 = (const float*)d_in[14];
    const float* ar3 = (const float*)d_in[15];
    const float* bg3 = (const float*)d_in[16];
    const float* sw = (const float*)d_in[17];
    const float* sb = (const float*)d_in[18];
    const float* lw1 = (const float*)d_in[19];
    const float* lb1 = (const float*)d_in[20];
    const float* lw2 = (const float*)d_in[21];
    const float* lb2 = (const float*)d_in[22];
    const float* lw3 = (const float*)d_in[23];
    const float* lb3 = (const float*)d_in[24];
    float* out = (float*)d_out;

    char* ws = (char*)d_ws;
    size_t off = 0;
    auto alloc = [&](size_t bytes) -> char* {
        char* p = ws + off;
        off += (bytes + 255) & ~(size_t)255;
        return p;
    };
    _Float16* xhi = (_Float16*)alloc((size_t)N_NODES * HD * 2);
    _Float16* xlo = (_Float16*)alloc((size_t)N_NODES * HD * 2);
    float* xf32 = (float*)xhi;  // aliases xhi+xlo (disjoint lifetimes)
    _Float16* hhi = (_Float16*)alloc((size_t)N_NODES * HD * 2);
    _Float16* W1hi = (_Float16*)alloc((size_t)F_IN * HD * 2);
    _Float16* W1lo = (_Float16*)alloc((size_t)F_IN * HD * 2);
    _Float16* W2hi = (_Float16*)alloc((size_t)HD * HD * 2);
    _Float16* W2lo = (_Float16*)alloc((size_t)HD * HD * 2);
    _Float16* W3hi = (_Float16*)alloc((size_t)HD * HD * 2);
    _Float16* W3lo = (_Float16*)alloc((size_t)HD * HD * 2);
    float* el = (float*)alloc((size_t)N_NODES * 4 * 4);
    float* er = (float*)alloc((size_t)N_NODES * 4 * 4);
    float* wsc = (float*)alloc((size_t)N_NODES * 4);
    float* y0 = (float*)alloc((size_t)N_GRAPHS * 272 * 4);
    int* hist = (int*)alloc((size_t)N_NODES * 4);
    int* row_ptr = (int*)alloc((size_t)(N_NODES + 1) * 4);
    int* cursor = (int*)alloc((size_t)N_NODES * 4);
    int* csr_src = (int*)alloc((size_t)N_EDGES * 4);
    int* gstart = (int*)alloc((size_t)(N_GRAPHS + 1) * 4);
    int* bsums = (int*)alloc(256 * 4);
    (void)ws_size; (void)in_sizes; (void)n_in; (void)out_size;

    hipMemsetAsync(hist, 0, (size_t)N_NODES * 4, stream);

    // CSR build (by dst)
    hist_k<<<(N_EDGES + 255) / 256, 256, 0, stream>>>(dst, hist);
    int nb = (N_NODES + SCAN_BLOCK - 1) / SCAN_BLOCK;
    scan1_k<<<nb, SCAN_BLOCK, 0, stream>>>(hist, row_ptr, bsums);
    scan2_k<<<1, 256, 0, stream>>>(bsums, nb);
    scan3_k<<<(N_NODES + 255) / 256, 256, 0, stream>>>(row_ptr, bsums, cursor);
    scatter_k<<<(N_EDGES + 255) / 256, 256, 0, stream>>>(src, dst, cursor, csr_src);
    gbound_k<<<3, 256, 0, stream>>>(node_graph, gstart);

    // weight splits
    tcast_split_k<<<(F_IN * HD + 255) / 256, 256, 0, stream>>>(W1, W1hi, W1lo, F_IN);
    tcast_split_k<<<(HD * HD + 255) / 256, 256, 0, stream>>>(W2, W2hi, W2lo, HD);
    tcast_split_k<<<(HD * HD + 255) / 256, 256, 0, stream>>>(W3, W3hi, W3lo, HD);

    dim3 ggrid(HD / 128, (N_NODES + 63) / 64);
    int nwb = (N_NODES + 3) / 4;

    // layer 1 (fp32 A split inline)
    gemm_split_k<F_IN, true><<<ggrid, 256, 0, stream>>>((const void*)feats_node, nullptr, W1hi, W1lo, al1, ar1, hhi, el, er, N_NODES);
    gat_aggregate_k<0><<<nwb, 256, 0, stream>>>(hhi, el, er, csr_src, row_ptr, bg1, xhi, xlo, nullptr, nullptr, nullptr, nullptr);
    // layer 2
    gemm_split_k<HD, false><<<ggrid, 256, 0, stream>>>((const void*)xhi, xlo, W2hi, W2lo, al2, ar2, hhi, el, er, N_NODES);
    gat_aggregate_k<0><<<nwb, 256, 0, stream>>>(hhi, el, er, csr_src, row_ptr, bg2, xhi, xlo, nullptr, nullptr, nullptr, nullptr);
    // layer 3 (fp32 out + fused sigmoid score)
    gemm_split_k<HD, false><<<ggrid, 256, 0, stream>>>((const void*)xhi, xlo, W3hi, W3lo, al3, ar3, hhi, el, er, N_NODES);
    gat_aggregate_k<1><<<nwb, 256, 0, stream>>>(hhi, el, er, csr_src, row_ptr, bg3, nullptr, nullptr, xf32, sw, sb, wsc);

    // readout + MLP
    readout_k<<<N_GRAPHS, 256, 0, stream>>>(xf32, wsc, gstart, feats_graph, y0);
    mlp_k<<<N_GRAPHS, 128, 0, stream>>>(y0, lw1, lb1, lw2, lb2, lw3, lb3, out);
}

// Round 14
// 924.348 us; speedup vs baseline: 1.0442x; 1.0083x over previous
//
#include <hip/hip_runtime.h>

#define N_NODES 100000
#define N_EDGES 1600000
#define N_GRAPHS 512
#define F_IN 64
#define HD 256
#define EXTRA 16
#define SCAN_BLOCK 512

typedef float f32x4 __attribute__((ext_vector_type(4)));
typedef _Float16 f16x4 __attribute__((ext_vector_type(4)));
typedef _Float16 f16x8 __attribute__((ext_vector_type(8)));

__device__ __forceinline__ float selu_f(float x) {
    const float a = 1.6732632423543772f, sc = 1.0507009873554805f;
    return x > 0.f ? sc * x : sc * a * (__expf(x) - 1.f);
}

// ---------------- CSR build ----------------
__global__ __launch_bounds__(256) void hist_k(const int* __restrict__ dst, int* __restrict__ hist) {
    int j = blockIdx.x * 256 + threadIdx.x;
    if (j < N_EDGES) atomicAdd(&hist[dst[j]], 1);
}

__global__ __launch_bounds__(SCAN_BLOCK) void scan1_k(const int* __restrict__ hist,
                                                      int* __restrict__ row_ptr,
                                                      int* __restrict__ bsums) {
    __shared__ int sm[SCAN_BLOCK];
    int t = threadIdx.x;
    int i = blockIdx.x * SCAN_BLOCK + t;
    int v = (i < N_NODES) ? hist[i] : 0;
    sm[t] = v;
    __syncthreads();
    for (int off = 1; off < SCAN_BLOCK; off <<= 1) {
        int add = (t >= off) ? sm[t - off] : 0;
        __syncthreads();
        sm[t] += add;
        __syncthreads();
    }
    if (i < N_NODES) row_ptr[i] = sm[t] - v;
    if (t == SCAN_BLOCK - 1) bsums[blockIdx.x] = sm[t];
}

// merged scan2+scan3: each block re-scans the (<=256) block sums in LDS,
// finalizes row_ptr AND initializes cursor = row_ptr.
__global__ __launch_bounds__(256) void scan23_k(int* __restrict__ row_ptr, const int* __restrict__ bsums,
                                                int* __restrict__ cursor, int nb) {
    __shared__ int bs[256];
    int t = threadIdx.x;
    bs[t] = (t < nb) ? bsums[t] : 0;
    __syncthreads();
    for (int off = 1; off < 256; off <<= 1) {
        int add = (t >= off) ? bs[t - off] : 0;
        __syncthreads();
        bs[t] += add;
        __syncthreads();
    }
    int i = blockIdx.x * 256 + t;
    if (i < N_NODES) {
        int b = i / SCAN_BLOCK;
        int p = b > 0 ? bs[b - 1] : 0;
        int r = row_ptr[i] + p;
        row_ptr[i] = r;
        cursor[i] = r;
    }
    if (i == 0) row_ptr[N_NODES] = N_EDGES;
}

__global__ __launch_bounds__(256) void scatter_k(const int* __restrict__ src,
                                                 const int* __restrict__ dst,
                                                 int* __restrict__ cursor,
                                                 int* __restrict__ csr_src) {
    int j = blockIdx.x * 256 + threadIdx.x;
    if (j < N_EDGES) {
        int r = atomicAdd(&cursor[dst[j]], 1);
        csr_src[r] = src[j];
    }
}

// ---------------- fused prologue: weight splits (W1/W2/W3) + graph bounds ----------------
__device__ __forceinline__ void wsplit(const float* __restrict__ W, _Float16* __restrict__ Wh,
                                       _Float16* __restrict__ Wl, int idx, int K) {
    int n = idx / K, k = idx - n * K;
    float w = W[(size_t)k * HD + n];
    _Float16 hi = (_Float16)w;
    Wh[idx] = hi;
    Wl[idx] = (_Float16)(w - (float)hi);
}

__global__ __launch_bounds__(256) void prep_k(const float* __restrict__ W1,
                                              const float* __restrict__ W2,
                                              const float* __restrict__ W3,
                                              _Float16* __restrict__ W1h, _Float16* __restrict__ W1l,
                                              _Float16* __restrict__ W2h, _Float16* __restrict__ W2l,
                                              _Float16* __restrict__ W3h, _Float16* __restrict__ W3l,
                                              const int* __restrict__ node_graph,
                                              int* __restrict__ gstart) {
    int b = blockIdx.x, t = threadIdx.x;
    if (b < 64) {
        wsplit(W1, W1h, W1l, b * 256 + t, F_IN);
    } else if (b < 320) {
        wsplit(W2, W2h, W2l, (b - 64) * 256 + t, HD);
    } else if (b < 576) {
        wsplit(W3, W3h, W3l, (b - 320) * 256 + t, HD);
    } else {
        int g = (b - 576) * 256 + t;
        if (g > N_GRAPHS) return;
        int lo = 0, hi = N_NODES;
        while (lo < hi) {
            int mid = (lo + hi) >> 1;
            if (node_graph[mid] < g) lo = mid + 1; else hi = mid;
        }
        gstart[g] = lo;
    }
}

// ---------------- split-f16 MFMA GEMM: 64x128 tile, LDS-staged coalesced C writes ----------------
template <int K, bool F32A>
__global__ __launch_bounds__(256) void gemm_split_k(const void* __restrict__ Aptr,
                                                    const _Float16* __restrict__ Alo_p,
                                                    const _Float16* __restrict__ Bt_hi,
                                                    const _Float16* __restrict__ Bt_lo,
                                                    const float* __restrict__ al,
                                                    const float* __restrict__ ar,
                                                    _Float16* __restrict__ Chi,
                                                    float* __restrict__ el,
                                                    float* __restrict__ er, int M) {
    const int BM = 64, BN = 128, LDP = 40;
    __shared__ union {
        struct {
            _Float16 Ash[BM][LDP];
            _Float16 Asl[BM][LDP];
            _Float16 Bsh[BN][LDP];
            _Float16 Bsl[BN][LDP];
        } s;
        _Float16 ctile[BM][BN];
    } u;
    __shared__ float pl[4][64];
    __shared__ float pr[4][64];
    _Float16 (&Ash)[BM][LDP] = u.s.Ash;
    _Float16 (&Asl)[BM][LDP] = u.s.Asl;
    _Float16 (&Bsh)[BN][LDP] = u.s.Bsh;
    _Float16 (&Bsl)[BN][LDP] = u.s.Bsl;

    int tid = threadIdx.x;
    int w = tid >> 6, lane = tid & 63;
    int q = lane >> 4, l16 = lane & 15;
    int row0 = blockIdx.y * BM, col0 = blockIdx.x * BN;
    f32x4 acc[4][2] = {};

    int ar_ = tid >> 2, ao = (tid & 3) * 8;
    f16x8 rAh, rAl, rBh[2], rBl[2];

    auto load_tile = [&](int k0) {
        int gr = row0 + ar_;
        if constexpr (F32A) {
            const float* A32 = (const float*)Aptr;
            float vv[8] = {};
            if (gr < M) {
                float4 va = *(const float4*)(A32 + (size_t)gr * K + k0 + ao);
                float4 vb = *(const float4*)(A32 + (size_t)gr * K + k0 + ao + 4);
                vv[0] = va.x; vv[1] = va.y; vv[2] = va.z; vv[3] = va.w;
                vv[4] = vb.x; vv[5] = vb.y; vv[6] = vb.z; vv[7] = vb.w;
            }
            f16x8 h, l;
#pragma unroll
            for (int i = 0; i < 8; i++) {
                h[i] = (_Float16)vv[i];
                l[i] = (_Float16)(vv[i] - (float)h[i]);
            }
            rAh = h; rAl = l;
        } else {
            const _Float16* Ahi = (const _Float16*)Aptr;
            f16x8 vh = {}, vl = {};
            if (gr < M) {
                vh = *(const f16x8*)(Ahi + (size_t)gr * K + k0 + ao);
                vl = *(const f16x8*)(Alo_p + (size_t)gr * K + k0 + ao);
            }
            rAh = vh; rAl = vl;
        }
#pragma unroll
        for (int c = 0; c < 2; c++) {
            int cc = tid + c * 256;
            int br = cc >> 2, bo = (cc & 3) * 8;
            int gb = col0 + br;
            rBh[c] = *(const f16x8*)(Bt_hi + (size_t)gb * K + k0 + bo);
            rBl[c] = *(const f16x8*)(Bt_lo + (size_t)gb * K + k0 + bo);
        }
    };
    auto store_tile = [&]() {
        *(f16x8*)&Ash[ar_][ao] = rAh;
        *(f16x8*)&Asl[ar_][ao] = rAl;
#pragma unroll
        for (int c = 0; c < 2; c++) {
            int cc = tid + c * 256;
            int br = cc >> 2, bo = (cc & 3) * 8;
            *(f16x8*)&Bsh[br][bo] = rBh[c];
            *(f16x8*)&Bsl[br][bo] = rBl[c];
        }
    };

    load_tile(0);
    store_tile();
    __syncthreads();

    for (int k0 = 0; k0 < K; k0 += 32) {
        bool more = (k0 + 32) < K;
        if (more) load_tile(k0 + 32);

        f16x8 ah[4], alo2[4], bh[2], bl[2];
#pragma unroll
        for (int mf = 0; mf < 4; mf++) {
            int m = mf * 16 + l16;
            ah[mf] = *(const f16x8*)&Ash[m][q * 8];
            alo2[mf] = *(const f16x8*)&Asl[m][q * 8];
        }
#pragma unroll
        for (int nf = 0; nf < 2; nf++) {
            int n = w * 32 + nf * 16 + l16;
            bh[nf] = *(const f16x8*)&Bsh[n][q * 8];
            bl[nf] = *(const f16x8*)&Bsl[n][q * 8];
        }
#pragma unroll
        for (int mf = 0; mf < 4; mf++)
#pragma unroll
            for (int nf = 0; nf < 2; nf++) {
                acc[mf][nf] = __builtin_amdgcn_mfma_f32_16x16x32_f16(ah[mf], bh[nf], acc[mf][nf], 0, 0, 0);
                acc[mf][nf] = __builtin_amdgcn_mfma_f32_16x16x32_f16(ah[mf], bl[nf], acc[mf][nf], 0, 0, 0);
                acc[mf][nf] = __builtin_amdgcn_mfma_f32_16x16x32_f16(alo2[mf], bh[nf], acc[mf][nf], 0, 0, 0);
            }
        if (more) {
            __syncthreads();
            store_tile();
            __syncthreads();
        }
    }

    __syncthreads();

    const int hh = (col0 >> 6) + (w >> 1);
    float alv[2], arv[2];
#pragma unroll
    for (int nf = 0; nf < 2; nf++) {
        int d = (w & 1) * 32 + nf * 16 + l16;
        alv[nf] = al[hh * 64 + d];
        arv[nf] = ar[hh * 64 + d];
    }
#pragma unroll
    for (int mf = 0; mf < 4; mf++) {
#pragma unroll
        for (int i = 0; i < 4; i++) {
            int rl = mf * 16 + q * 4 + i;
            float e_l = 0.f, e_r = 0.f;
#pragma unroll
            for (int nf = 0; nf < 2; nf++) {
                float v = acc[mf][nf][i];
                u.ctile[rl][w * 32 + nf * 16 + l16] = (_Float16)v;
                e_l = fmaf(v, alv[nf], e_l);
                e_r = fmaf(v, arv[nf], e_r);
            }
#pragma unroll
            for (int off = 1; off < 16; off <<= 1) {
                e_l += __shfl_xor(e_l, off, 64);
                e_r += __shfl_xor(e_r, off, 64);
            }
            if (l16 == 0) {
                pl[w][rl] = e_l;
                pr[w][rl] = e_r;
            }
        }
    }
    __syncthreads();
#pragma unroll
    for (int j = 0; j < 4; j++) {
        int c = tid + j * 256;
        int rr2 = c >> 4, co = (c & 15) * 8;
        int gr = row0 + rr2;
        if (gr < M)
            *(f16x8*)(Chi + (size_t)gr * HD + col0 + co) = *(const f16x8*)&u.ctile[rr2][co];
    }
    int h2 = (tid >> 6) & 1, rr = tid & 63;
    int grow = row0 + rr;
    if (grow < M) {
        if (tid < 128) el[(size_t)grow * 4 + (col0 >> 6) + h2] = pl[2 * h2][rr] + pl[2 * h2 + 1][rr];
        else           er[(size_t)grow * 4 + (col0 >> 6) + h2] = pr[2 * h2][rr] + pr[2 * h2 + 1][rr];
    }
}

// ---------------- GAT aggregation (R9: barrier-free, 8-deep prefetch) ----------------
template <int OUT>
__global__ __launch_bounds__(256) void gat_aggregate_k(const _Float16* __restrict__ hb,
                                                       const float* __restrict__ el,
                                                       const float* __restrict__ er,
                                                       const int* __restrict__ csr_src,
                                                       const int* __restrict__ row_ptr,
                                                       const float* __restrict__ bias,
                                                       _Float16* __restrict__ xhi,
                                                       _Float16* __restrict__ xlo,
                                                       float* __restrict__ xf32,
                                                       const float* __restrict__ sw,
                                                       const float* __restrict__ sb,
                                                       float* __restrict__ wsc) {
    __shared__ float wlds[4][64][4];
    __shared__ int snlds[4][64];
    int wv = threadIdx.x >> 6;
    int lane = threadIdx.x & 63;
    int v = blockIdx.x * 4 + wv;
    bool valid = v < N_NODES;
    int vc = valid ? v : 0;
    int rs = row_ptr[vc];
    int deg = valid ? row_ptr[vc + 1] - rs : 0;
    float4 erv = make_float4(0.f, 0.f, 0.f, 0.f);
    if (valid) erv = *(const float4*)(er + (size_t)vc * 4);

    int head = lane >> 4;
    float inv_den = 1.f;
    float m_h = 0.f, er_h = 0.f;
    f16x4 hv_pre[8];
    int nb0 = 0;

    if (deg <= 64) {
        float e0 = -1e30f, e1 = -1e30f, e2 = -1e30f, e3 = -1e30f;
        int my_sn = 0;
        if (lane < deg) {
            my_sn = csr_src[rs + lane];
            float4 elv = *(const float4*)(el + (size_t)my_sn * 4);
            float t0 = elv.x + erv.x, t1 = elv.y + erv.y, t2 = elv.z + erv.z, t3 = elv.w + erv.w;
            e0 = t0 > 0.f ? t0 : 0.2f * t0;
            e1 = t1 > 0.f ? t1 : 0.2f * t1;
            e2 = t2 > 0.f ? t2 : 0.2f * t2;
            e3 = t3 > 0.f ? t3 : 0.2f * t3;
        }
        nb0 = deg < 8 ? deg : 8;
#pragma unroll
        for (int u = 0; u < 8; u++) {
            int snb = __shfl(my_sn, u, 64);
            if (u < nb0) hv_pre[u] = *(const f16x4*)(hb + (size_t)snb * HD + lane * 4);
        }
        float m0 = e0, m1 = e1, m2 = e2, m3 = e3;
        for (int off = 1; off < deg; off <<= 1) {
            m0 = fmaxf(m0, __shfl_xor(m0, off, 64));
            m1 = fmaxf(m1, __shfl_xor(m1, off, 64));
            m2 = fmaxf(m2, __shfl_xor(m2, off, 64));
            m3 = fmaxf(m3, __shfl_xor(m3, off, 64));
        }
        float p0 = 0.f, p1 = 0.f, p2 = 0.f, p3 = 0.f;
        if (lane < deg) {
            p0 = __expf(e0 - m0); p1 = __expf(e1 - m1);
            p2 = __expf(e2 - m2); p3 = __expf(e3 - m3);
        }
        float s0 = p0, s1 = p1, s2 = p2, s3 = p3;
        for (int off = 1; off < deg; off <<= 1) {
            s0 += __shfl_xor(s0, off, 64);
            s1 += __shfl_xor(s1, off, 64);
            s2 += __shfl_xor(s2, off, 64);
            s3 += __shfl_xor(s3, off, 64);
        }
        float d0 = __shfl(s0, 0, 64), d1 = __shfl(s1, 0, 64);
        float d2 = __shfl(s2, 0, 64), d3 = __shfl(s3, 0, 64);
        float dh = head == 0 ? d0 : head == 1 ? d1 : head == 2 ? d2 : d3;
        inv_den = 1.f / fmaxf(dh, 1e-9f);
        if (lane < deg) {
            wlds[wv][lane][0] = p0;
            wlds[wv][lane][1] = p1;
            wlds[wv][lane][2] = p2;
            wlds[wv][lane][3] = p3;
            snlds[wv][lane] = my_sn;
        }
        // no barrier: wave-private LDS slice
    } else {
        float m[4] = {-1e30f, -1e30f, -1e30f, -1e30f};
        float s[4] = {0.f, 0.f, 0.f, 0.f};
        for (int t = lane; t < deg; t += 64) {
            int sn = csr_src[rs + t];
            float4 elv = *(const float4*)(el + (size_t)sn * 4);
            float e[4];
            e[0] = elv.x + erv.x; e[1] = elv.y + erv.y; e[2] = elv.z + erv.z; e[3] = elv.w + erv.w;
#pragma unroll
            for (int hh = 0; hh < 4; hh++) {
                float ev = e[hh] > 0.f ? e[hh] : 0.2f * e[hh];
                float mn = fmaxf(m[hh], ev);
                s[hh] = s[hh] * __expf(m[hh] - mn) + __expf(ev - mn);
                m[hh] = mn;
            }
        }
#pragma unroll
        for (int off = 32; off >= 1; off >>= 1) {
#pragma unroll
            for (int hh = 0; hh < 4; hh++) {
                float mo = __shfl_xor(m[hh], off, 64);
                float so = __shfl_xor(s[hh], off, 64);
                float mn = fmaxf(m[hh], mo);
                s[hh] = s[hh] * __expf(m[hh] - mn) + so * __expf(mo - mn);
                m[hh] = mn;
            }
        }
        m_h = head == 0 ? m[0] : head == 1 ? m[1] : head == 2 ? m[2] : m[3];
        float dh = head == 0 ? s[0] : head == 1 ? s[1] : head == 2 ? s[2] : s[3];
        er_h = head == 0 ? erv.x : head == 1 ? erv.y : head == 2 ? erv.z : erv.w;
        inv_den = 1.f / fmaxf(dh, 1e-9f);
    }

    float a0 = 0.f, a1 = 0.f, a2 = 0.f, a3 = 0.f;
    if (deg <= 64) {
#pragma unroll
        for (int u = 0; u < 8; u++) {
            if (u < nb0) {
                float w = wlds[wv][u][head];
                a0 = fmaf(w, (float)hv_pre[u].x, a0);
                a1 = fmaf(w, (float)hv_pre[u].y, a1);
                a2 = fmaf(w, (float)hv_pre[u].z, a2);
                a3 = fmaf(w, (float)hv_pre[u].w, a3);
            }
        }
        int t = 8;
        for (; t + 8 <= deg; t += 8) {
            int sn[8];
            float w[8];
#pragma unroll
            for (int u = 0; u < 8; u++) {
                sn[u] = snlds[wv][t + u];
                w[u] = wlds[wv][t + u][head];
            }
            f16x4 hv[8];
#pragma unroll
            for (int u = 0; u < 8; u++)
                hv[u] = *(const f16x4*)(hb + (size_t)sn[u] * HD + lane * 4);
#pragma unroll
            for (int u = 0; u < 8; u++) {
                a0 = fmaf(w[u], (float)hv[u].x, a0);
                a1 = fmaf(w[u], (float)hv[u].y, a1);
                a2 = fmaf(w[u], (float)hv[u].z, a2);
                a3 = fmaf(w[u], (float)hv[u].w, a3);
            }
        }
        for (; t < deg; t++) {
            int sn = snlds[wv][t];
            float w = wlds[wv][t][head];
            f16x4 hv = *(const f16x4*)(hb + (size_t)sn * HD + lane * 4);
            a0 = fmaf(w, (float)hv.x, a0);
            a1 = fmaf(w, (float)hv.y, a1);
            a2 = fmaf(w, (float)hv.z, a2);
            a3 = fmaf(w, (float)hv.w, a3);
        }
    } else {
        for (int t = 0; t < deg; t++) {
            int sn = csr_src[rs + t];
            float e = el[(size_t)sn * 4 + head] + er_h;
            e = e > 0.f ? e : 0.2f * e;
            float w = __expf(e - m_h);
            f16x4 hv = *(const f16x4*)(hb + (size_t)sn * HD + lane * 4);
            a0 = fmaf(w, (float)hv.x, a0);
            a1 = fmaf(w, (float)hv.y, a1);
            a2 = fmaf(w, (float)hv.z, a2);
            a3 = fmaf(w, (float)hv.w, a3);
        }
    }
    float4 bv = *(const float4*)(bias + lane * 4);
    float4 o;
    o.x = selu_f(fmaf(a0, inv_den, bv.x));
    o.y = selu_f(fmaf(a1, inv_den, bv.y));
    o.z = selu_f(fmaf(a2, inv_den, bv.z));
    o.w = selu_f(fmaf(a3, inv_den, bv.w));

    if constexpr (OUT == 0) {
        f16x4 oh, ol;
        oh.x = (_Float16)o.x; ol.x = (_Float16)(o.x - (float)oh.x);
        oh.y = (_Float16)o.y; ol.y = (_Float16)(o.y - (float)oh.y);
        oh.z = (_Float16)o.z; ol.z = (_Float16)(o.z - (float)oh.z);
        oh.w = (_Float16)o.w; ol.w = (_Float16)(o.w - (float)oh.w);
        if (valid) {
            *(f16x4*)(xhi + (size_t)v * HD + lane * 4) = oh;
            *(f16x4*)(xlo + (size_t)v * HD + lane * 4) = ol;
        }
    } else {
        if (valid) *(float4*)(xf32 + (size_t)v * HD + lane * 4) = o;
        float4 sv = *(const float4*)(sw + lane * 4);
        float p = o.x * sv.x + o.y * sv.y + o.z * sv.z + o.w * sv.w;
#pragma unroll
        for (int off = 1; off < 64; off <<= 1) p += __shfl_xor(p, off, 64);
        if (lane == 0 && valid) wsc[v] = 1.f / (1.f + __expf(-(p + sb[0])));
    }
}

// ---------------- readout: 4 chunk-partials per graph (deterministic) ----------------
__global__ __launch_bounds__(256) void readout_part_k(const float* __restrict__ x,
                                                      const float* __restrict__ wsc,
                                                      const int* __restrict__ gstart,
                                                      float* __restrict__ y0p) {
    int g = blockIdx.x >> 2, c = blockIdx.x & 3;
    int f = threadIdx.x;
    int s0 = gstart[g], e0 = gstart[g + 1];
    int len = e0 - s0;
    int cs = s0 + (len * c) / 4, ce = s0 + (len * (c + 1)) / 4;
    float num = 0.f, den = 0.f;
#pragma unroll 4
    for (int n = cs; n < ce; n++) {
        float wn = wsc[n];
        num = fmaf(wn, x[(size_t)n * HD + f], num);
        den += wn;
    }
    float* dst = y0p + (size_t)(g * 4 + c) * 257;
    dst[f] = num;
    if (f == 0) dst[256] = den;
}

__global__ __launch_bounds__(128) void mlp_k(const float* __restrict__ y0p,
                                             const float* __restrict__ fg,
                                             const float* __restrict__ lw1, const float* __restrict__ lb1,
                                             const float* __restrict__ lw2, const float* __restrict__ lb2,
                                             const float* __restrict__ lw3, const float* __restrict__ lb3,
                                             float* __restrict__ out) {
    __shared__ float y0s[272];
    __shared__ float y1s[128];
    int g = blockIdx.x, t = threadIdx.x;
    const float* p0 = y0p + (size_t)(g * 4 + 0) * 257;
    const float* p1 = y0p + (size_t)(g * 4 + 1) * 257;
    const float* p2 = y0p + (size_t)(g * 4 + 2) * 257;
    const float* p3 = y0p + (size_t)(g * 4 + 3) * 257;
    float den = p0[256] + p1[256] + p2[256] + p3[256];
    float invden = 1.f / fmaxf(den, 1e-9f);
    for (int i = t; i < 256; i += 128)
        y0s[i] = (p0[i] + p1[i] + p2[i] + p3[i]) * invden;
    if (t < EXTRA) y0s[256 + t] = fg[g * EXTRA + t];
    __syncthreads();
    float acc = lb1[t];
    for (int k = 0; k < 272; k++) acc = fmaf(y0s[k], lw1[k * 128 + t], acc);
    y1s[t] = selu_f(acc);
    __syncthreads();
    if (t < 64) {
        float a2 = lb2[t];
        for (int k = 0; k < 128; k++) a2 = fmaf(y1s[k], lw2[k * 64 + t], a2);
        float v2 = selu_f(a2);
        float p = v2 * lw3[t];
#pragma unroll
        for (int off = 1; off < 64; off <<= 1) p += __shfl_xor(p, off, 64);
        if (t == 0) out[g] = p + lb3[0];
    }
}

extern "C" void kernel_launch(void* const* d_in, const int* in_sizes, int n_in,
                              void* d_out, int out_size, void* d_ws, size_t ws_size,
                              hipStream_t stream) {
    const int* src = (const int*)d_in[0];
    const int* dst = (const int*)d_in[1];
    const int* node_graph = (const int*)d_in[2];
    const float* feats_node = (const float*)d_in[3];
    const float* feats_graph = (const float*)d_in[4];
    const float* W1 = (const float*)d_in[5];
    const float* al1 = (const float*)d_in[6];
    const float* ar1 = (const float*)d_in[7];
    const float* bg1 = (const float*)d_in[8];
    const float* W2 = (const float*)d_in[9];
    const float* al2 = (const float*)d_in[10];
    const float* ar2 = (const float*)d_in[11];
    const float* bg2 = (const float*)d_in[12];
    const float* W3 = (const float*)d_in[13];
    const float* al3 = (const float*)d_in[14];
    const float* ar3 = (const float*)d_in[15];
    const float* bg3 = (const float*)d_in[16];
    const float* sw = (const float*)d_in[17];
    const float* sb = (const float*)d_in[18];
    const float* lw1 = (const float*)d_in[19];
    const float* lb1 = (const float*)d_in[20];
    const float* lw2 = (const float*)d_in[21];
    const float* lb2 = (const float*)d_in[22];
    const float* lw3 = (const float*)d_in[23];
    const float* lb3 = (const float*)d_in[24];
    float* out = (float*)d_out;

    char* ws = (char*)d_ws;
    size_t off = 0;
    auto alloc = [&](size_t bytes) -> char* {
        char* p = ws + off;
        off += (bytes + 255) & ~(size_t)255;
        return p;
    };
    _Float16* xhi = (_Float16*)alloc((size_t)N_NODES * HD * 2);
    _Float16* xlo = (_Float16*)alloc((size_t)N_NODES * HD * 2);
    float* xf32 = (float*)xhi;  // aliases xhi+xlo (disjoint lifetimes)
    _Float16* hhi = (_Float16*)alloc((size_t)N_NODES * HD * 2);
    _Float16* W1hi = (_Float16*)alloc((size_t)F_IN * HD * 2);
    _Float16* W1lo = (_Float16*)alloc((size_t)F_IN * HD * 2);
    _Float16* W2hi = (_Float16*)alloc((size_t)HD * HD * 2);
    _Float16* W2lo = (_Float16*)alloc((size_t)HD * HD * 2);
    _Float16* W3hi = (_Float16*)alloc((size_t)HD * HD * 2);
    _Float16* W3lo = (_Float16*)alloc((size_t)HD * HD * 2);
    float* el = (float*)alloc((size_t)N_NODES * 4 * 4);
    float* er = (float*)alloc((size_t)N_NODES * 4 * 4);
    float* wsc = (float*)alloc((size_t)N_NODES * 4);
    float* y0p = (float*)alloc((size_t)N_GRAPHS * 4 * 257 * 4);
    int* hist = (int*)alloc((size_t)N_NODES * 4);
    int* row_ptr = (int*)alloc((size_t)(N_NODES + 1) * 4);
    int* cursor = (int*)alloc((size_t)N_NODES * 4);
    int* csr_src = (int*)alloc((size_t)N_EDGES * 4);
    int* gstart = (int*)alloc((size_t)(N_GRAPHS + 1) * 4);
    int* bsums = (int*)alloc(256 * 4);
    (void)ws_size; (void)in_sizes; (void)n_in; (void)out_size;

    hipMemsetAsync(hist, 0, (size_t)N_NODES * 4, stream);

    // CSR build (by dst)
    hist_k<<<(N_EDGES + 255) / 256, 256, 0, stream>>>(dst, hist);
    int nb = (N_NODES + SCAN_BLOCK - 1) / SCAN_BLOCK;  // 196 <= 256
    scan1_k<<<nb, SCAN_BLOCK, 0, stream>>>(hist, row_ptr, bsums);
    scan23_k<<<(N_NODES + 255) / 256, 256, 0, stream>>>(row_ptr, bsums, cursor, nb);
    scatter_k<<<(N_EDGES + 255) / 256, 256, 0, stream>>>(src, dst, cursor, csr_src);

    // fused prologue: weight splits + graph bounds
    prep_k<<<579, 256, 0, stream>>>(W1, W2, W3, W1hi, W1lo, W2hi, W2lo, W3hi, W3lo, node_graph, gstart);

    dim3 ggrid(HD / 128, (N_NODES + 63) / 64);
    int nwb = (N_NODES + 3) / 4;

    // layer 1 (fp32 A split inline)
    gemm_split_k<F_IN, true><<<ggrid, 256, 0, stream>>>((const void*)feats_node, nullptr, W1hi, W1lo, al1, ar1, hhi, el, er, N_NODES);
    gat_aggregate_k<0><<<nwb, 256, 0, stream>>>(hhi, el, er, csr_src, row_ptr, bg1, xhi, xlo, nullptr, nullptr, nullptr, nullptr);
    // layer 2
    gemm_split_k<HD, false><<<ggrid, 256, 0, stream>>>((const void*)xhi, xlo, W2hi, W2lo, al2, ar2, hhi, el, er, N_NODES);
    gat_aggregate_k<0><<<nwb, 256, 0, stream>>>(hhi, el, er, csr_src, row_ptr, bg2, xhi, xlo, nullptr, nullptr, nullptr, nullptr);
    // layer 3 (fp32 out + fused sigmoid score)
    gemm_split_k<HD, false><<<ggrid, 256, 0, stream>>>((const void*)xhi, xlo, W3hi, W3lo, al3, ar3, hhi, el, er, N_NODES);
    gat_aggregate_k<1><<<nwb, 256, 0, stream>>>(hhi, el, er, csr_src, row_ptr, bg3, nullptr, nullptr, xf32, sw, sb, wsc);

    // readout (4 partials/graph) + MLP
    readout_part_k<<<N_GRAPHS * 4, 256, 0, stream>>>(xf32, wsc, gstart, y0p);
    mlp_k<<<N_GRAPHS, 128, 0, stream>>>(y0p, feats_graph, lw1, lb1, lw2, lb2, lw3, lb3, out);
}